// Round 3
// baseline (628.823 us; speedup 1.0000x reference)
//
#include <hip/hip_runtime.h>
#include <math.h>

#define NN   50000
#define TT   16
#define EE   800000
#define BB   2000
#define EMBD 32
#define ENC  64
#define DEC  128
#define OUTL 25
#define BN_EPS 1e-5f

typedef short v8s __attribute__((ext_vector_type(8)));
typedef float v4f __attribute__((ext_vector_type(4)));
#define MFMA16(a,b,c) __builtin_amdgcn_mfma_f32_16x16x32_bf16((a),(b),(c),0,0,0)

__device__ __forceinline__ float lrelu(float v){ return v >= 0.f ? v : 0.1f*v; }
__device__ __forceinline__ float fsig(float v){ return __builtin_amdgcn_rcpf(1.f + __expf(-v)); }
__device__ __forceinline__ float ftanh(float v){ return 2.f*__builtin_amdgcn_rcpf(1.f + __expf(-2.f*v)) - 1.f; }
__device__ __forceinline__ float fsoftplus(float v){
    return v > 15.f ? v : __logf(1.f + __expf(v));
}
__device__ __forceinline__ float hsum(float4 a){ return (a.x+a.y)+(a.z+a.w); }

__device__ __forceinline__ unsigned short f2bf(float f){
    unsigned u = __float_as_uint(f);
    u = u + 0x7FFFu + ((u>>16)&1u);
    return (unsigned short)(u>>16);
}
__device__ __forceinline__ float bf2f(unsigned short s){ return __uint_as_float(((unsigned)s)<<16); }

// truncation-based hi/lo split (R12): hi = truncated bf16, lo = bf16 of the
// exact residual. ~4 VALU ops vs ~8 for the RNE pair; residual compensates
// truncation so net precision matches (weights are hi-only bf16 anyway).
__device__ __forceinline__ void tsplit(float v, unsigned short& hi, unsigned short& lo){
    unsigned u = __float_as_uint(v);
    hi = (unsigned short)(u >> 16);
    float r = v - __uint_as_float(u & 0xFFFF0000u);
    lo = (unsigned short)(__float_as_uint(r) >> 16);
}

__device__ __forceinline__ v8s as_v8s(int4 v){
    union { int4 i; v8s s; } u; u.i = v; return u.s;
}

__device__ __forceinline__ void cvt8(const float* p, v8s& hi, v8s& lo){
    float4 a0 = *(const float4*)p;
    float4 a1 = *(const float4*)(p+4);
    float av[8] = {a0.x,a0.y,a0.z,a0.w,a1.x,a1.y,a1.z,a1.w};
#pragma unroll
    for (int j=0;j<8;j++){
        unsigned short h = f2bf(av[j]);
        hi[j] = (short)h;
        lo[j] = (short)f2bf(av[j] - bf2f(h));
    }
}
// reconstruct hi+lo, lrelu, re-split
__device__ __forceinline__ void lrelu_resplit(v8s hh, v8s hl, v8s& oh, v8s& ol){
#pragma unroll
    for (int j=0;j<8;j++){
        float v = bf2f((unsigned short)hh[j]) + bf2f((unsigned short)hl[j]);
        float a = lrelu(v);
        unsigned short h = f2bf(a);
        oh[j] = (short)h;
        ol[j] = (short)f2bf(a - bf2f(h));
    }
}

// ---------------- fused packing helpers ----------------
__device__ __forceinline__ void pf_item(const float* W, int K, int KB, int i,
                                        unsigned short* out){
    int l = i & 63, fb = i >> 6;
    int kb = fb % KB, nt = fb / KB;
    int n = nt*16 + (l&15);
    int k0 = kb*32 + ((l>>4)*8);
#pragma unroll
    for (int j=0;j<8;j++) out[i*8+j] = f2bf(W[(size_t)n*K + k0 + j]);
}
__device__ __forceinline__ void phl_item(const float* W, int K, int KB, int i,
                                         unsigned short* hi, unsigned short* lo){
    int l = i & 63, fb = i >> 6;
    int kb = fb % KB, nt = fb / KB;
    int n = nt*16 + (l&15);
    int k0 = kb*32 + ((l>>4)*8);
#pragma unroll
    for (int j=0;j<8;j++){
        float v = W[(size_t)n*K + k0 + j];
        unsigned short h = f2bf(v);
        hi[i*8+j] = h;
        lo[i*8+j] = f2bf(v - bf2f(h));
    }
}
__device__ __forceinline__ void pcat_item(const float* Wa, const float* Wb,
                                          int K1, int K, int KB, int i,
                                          unsigned short* out){
    int l = i & 63, fb = i >> 6;
    int kb = fb % KB, nt = fb / KB;
    int n = nt*16 + (l&15);
    int k0 = kb*32 + ((l>>4)*8);
#pragma unroll
    for (int j=0;j<8;j++){
        int k = k0 + j;
        float v = (k < K1) ? Wa[(size_t)n*K1 + k] : Wb[(size_t)n*(K-K1) + (k-K1)];
        out[i*8+j] = f2bf(v);
    }
}
__device__ __forceinline__ void pproj_item(const float* Wf, const float* Ws, int i,
                                           unsigned short* hi, unsigned short* lo){
    int l = i & 63, fb = i >> 6;
    int kb = fb & 1, nt = fb >> 1;
    int n = nt*16 + (l&15);
    int d = n >> 6, c = n & 63;
    const float* W = (d < 2) ? Wf : Ws;
    int k0 = (d&1)*64 + kb*32 + ((l>>4)*8);
#pragma unroll
    for (int j=0;j<8;j++){
        float v = W[c*130 + k0 + j];
        unsigned short h = f2bf(v);
        hi[i*8+j] = h;
        lo[i*8+j] = f2bf(v - bf2f(h));
    }
}

// ---------------- all weight prep in ONE dispatch ----------------
__global__ void pack_all(
    const float* __restrict__ gWih, const float* __restrict__ gWhh,
    const float* __restrict__ Wdyn,
    const float* __restrict__ l0Whh, const float* __restrict__ l1Wih,
    const float* __restrict__ l1Whh, const float* __restrict__ l0Wih,
    const float* __restrict__ c1Wf, const float* __restrict__ c1Ws,
    const float* __restrict__ c2Wf, const float* __restrict__ c2Ws,
    unsigned short* __restrict__ pWih, unsigned short* __restrict__ pWhh,
    unsigned short* __restrict__ pWdyn,
    unsigned short* __restrict__ B0h, unsigned short* __restrict__ B1h,
    unsigned short* __restrict__ P1h, unsigned short* __restrict__ P1l,
    unsigned short* __restrict__ P2h, unsigned short* __restrict__ P2l,
    unsigned short* __restrict__ GIh, unsigned short* __restrict__ GIl,
    int* __restrict__ cnt, int* __restrict__ gtot)
{
    int i = blockIdx.x*256 + threadIdx.x;
    if (i < 768){ pf_item(gWih, 32, 1, i, pWih); return; }   i -= 768;
    if (i < 1536){ pf_item(gWhh, 64, 2, i, pWhh); return; }  i -= 1536;
    if (i < 512){ pf_item(Wdyn, 64, 2, i, pWdyn); return; }  i -= 512;
    if (i < 8192){ pcat_item(l0Whh, l0Whh, 128, 128, 4, i, B0h); return; } i -= 8192;
    if (i < 16384){ pcat_item(l1Wih, l1Whh, 128, 256, 8, i, B1h); return; } i -= 16384;
    if (i < 2048){ pproj_item(c1Wf, c1Ws, i, P1h, P1l); return; } i -= 2048;
    if (i < 2048){ pproj_item(c2Wf, c2Ws, i, P2h, P2l); return; } i -= 2048;
    if (i < 8192){ phl_item(l0Wih, 128, 4, i, GIh, GIl); return; } i -= 8192;
    if (i < NN){ cnt[i] = 0; return; } i -= NN;
    if (i < 1){ gtot[0] = 0; return; }
}
#define PACK_TOTAL (768+1536+512+8192+16384+2048+2048+8192+NN+1)

// ---------------- GRU encoder v7: 2 waves, 2 independent node-groups/wave ----------------
// R14 theory: v6 at VALUBusy 54 / MfmaUtil 23 / occ 17.6% (1.4 waves/SIMD) is
// latency-bound inside each wave (MFMA->gates dependency, 6-deep MFMA chains,
// nothing resident to fill the gaps). v7: each block = 32 nodes in two
// independent groups A,B; each wave runs BOTH groups:
//  - every B-fragment weight load now feeds 4 MFMAs (A-hi,A-lo,B-hi,B-lo):
//    half the loads per MFMA, and two independent accumulator chains
//    interleave to hide MFMA latency.
//  - gate VALU of one group overlaps MFMA/LDS latency of the other.
//  - biases/Wip regs shared between groups; ONE barrier/step still.
// Tail: 3125 groups is odd -> last block's B is clamped to group 3124 with
// stores predicated off (loads stay in-range, results discarded).
__global__ __launch_bounds__(128) void encoder_mfma(
    const float* __restrict__ x,
    const float* __restrict__ Wip, const float* __restrict__ bip,
    const unsigned short* __restrict__ pWih,
    const unsigned short* __restrict__ pWhh,
    const float* __restrict__ bih, const float* __restrict__ bhh,
    const unsigned short* __restrict__ pWdyn,
    const float* __restrict__ bdyn,
    float* __restrict__ hist)
{
    __shared__ float sxt[2][512];                              // x transposed [t][m][c] per group
    __shared__ unsigned short hfh[2][2048], hfl[2][2048];      // dbuf x group h A-frags
    const int tid = threadIdx.x;
    const int l   = tid & 63;
    const int w   = tid >> 6;
    const int ln  = l & 15, q = l >> 4;
    const int blk = blockIdx.x;

    const int gA = 2*blk;
    const bool bvalid = (2*blk + 1) < (NN/16);
    const int gB = bvalid ? (2*blk + 1) : (NN/16 - 1);

    // coalesced x load + transpose into [t][m][c]
    {
        const size_t baseA = (size_t)gA*512;
        const size_t baseB = (size_t)gB*512;
        for (int idx = tid; idx < 1024; idx += 128){
            int g = idx >> 9, r = idx & 511;
            int m = r >> 5, rr = r & 31;                       // rr = t*2 + c
            sxt[g][(rr>>1)*32 + m*2 + (rr&1)] = x[(g ? baseB : baseA) + r];
        }
    }
    for (int i = tid; i < 2048; i += 128){
        hfh[0][i]=0; hfl[0][i]=0; hfh[1][i]=0; hfl[1][i]=0;
    }

    // per-lane input-projection weights for k = q*8+j (shared by both groups)
    float w0[8], w1[8], bk[8];
#pragma unroll
    for (int j = 0; j < 8; j++){
        int k = q*8 + j;
        w0[j] = Wip[2*k]; w1[j] = Wip[2*k+1]; bk[j] = bip[k];
    }

    float bR[2], bZ[2], bNI[2], bNH[2];
    float hprevA[2][4], hprevB[2][4];
#pragma unroll
    for (int u = 0; u < 2; u++){
        int g = 2*w + u;
        int c = g*16 + ln;
        bR[u]  = bih[c]       + bhh[c];
        bZ[u]  = bih[64 + c]  + bhh[64 + c];
        bNI[u] = bih[128 + c];
        bNH[u] = bhh[128 + c];
#pragma unroll
        for (int i = 0; i < 4; i++){ hprevA[u][i]=0.f; hprevB[u][i]=0.f; }
    }
    const v8s* FIH = (const v8s*)pWih;
    const v8s* FHH = (const v8s*)pWhh;
    const v8s* FDY = (const v8s*)pWdyn;
    __syncthreads();

    int p = 0;
#pragma unroll 1
    for (int t = 0; t < TT; t++){
        // ---- e A-frags in registers for both groups ----
        float2 xvA = *(const float2*)&sxt[0][t*32 + ln*2];
        float2 xvB = *(const float2*)&sxt[1][t*32 + ln*2];
        v8s ehA, elA, ehB, elB;
#pragma unroll
        for (int j = 0; j < 8; j++){
            float eA = lrelu(w0[j]*xvA.x + w1[j]*xvA.y + bk[j]);
            float eB = lrelu(w0[j]*xvB.x + w1[j]*xvB.y + bk[j]);
            unsigned short h_, l_;
            tsplit(eA, h_, l_); ehA[j]=(short)h_; elA[j]=(short)l_;
            tsplit(eB, h_, l_); ehB[j]=(short)h_; elB[j]=(short)l_;
        }
        v8s h0hA = *(const v8s*)&hfh[p][l*8];
        v8s h0lA = *(const v8s*)&hfl[p][l*8];
        v8s h1hA = *(const v8s*)&hfh[p][512 + l*8];
        v8s h1lA = *(const v8s*)&hfl[p][512 + l*8];
        v8s h0hB = *(const v8s*)&hfh[p][1024 + l*8];
        v8s h0lB = *(const v8s*)&hfl[p][1024 + l*8];
        v8s h1hB = *(const v8s*)&hfh[p][1536 + l*8];
        v8s h1lB = *(const v8s*)&hfl[p][1536 + l*8];
#pragma unroll
        for (int u = 0; u < 2; u++){
            int g = 2*w + u;
            v4f aRA = {bR[u],bR[u],bR[u],bR[u]},   aRB = aRA;
            v4f aZA = {bZ[u],bZ[u],bZ[u],bZ[u]},   aZB = aZA;
            v4f aNIA= {bNI[u],bNI[u],bNI[u],bNI[u]}, aNIB = aNIA;
            v4f aNHA= {bNH[u],bNH[u],bNH[u],bNH[u]}, aNHB = aNHA;
            v8s b;
            // each b-frag load feeds 4 MFMAs (A/B x hi/lo)
            b = FIH[(g   )*64 + l];
            aRA = MFMA16(ehA,b,aRA);  aRB = MFMA16(ehB,b,aRB);
            aRA = MFMA16(elA,b,aRA);  aRB = MFMA16(elB,b,aRB);
            b = FHH[(g*2+0)*64+l];
            aRA = MFMA16(h0hA,b,aRA); aRB = MFMA16(h0hB,b,aRB);
            aRA = MFMA16(h0lA,b,aRA); aRB = MFMA16(h0lB,b,aRB);
            b = FHH[(g*2+1)*64+l];
            aRA = MFMA16(h1hA,b,aRA); aRB = MFMA16(h1hB,b,aRB);
            aRA = MFMA16(h1lA,b,aRA); aRB = MFMA16(h1lB,b,aRB);
            b = FIH[(4+g )*64 + l];
            aZA = MFMA16(ehA,b,aZA);  aZB = MFMA16(ehB,b,aZB);
            aZA = MFMA16(elA,b,aZA);  aZB = MFMA16(elB,b,aZB);
            b = FHH[((4+g)*2+0)*64+l];
            aZA = MFMA16(h0hA,b,aZA); aZB = MFMA16(h0hB,b,aZB);
            aZA = MFMA16(h0lA,b,aZA); aZB = MFMA16(h0lB,b,aZB);
            b = FHH[((4+g)*2+1)*64+l];
            aZA = MFMA16(h1hA,b,aZA); aZB = MFMA16(h1hB,b,aZB);
            aZA = MFMA16(h1lA,b,aZA); aZB = MFMA16(h1lB,b,aZB);
            b = FIH[(8+g )*64 + l];
            aNIA= MFMA16(ehA,b,aNIA); aNIB= MFMA16(ehB,b,aNIB);
            aNIA= MFMA16(elA,b,aNIA); aNIB= MFMA16(elB,b,aNIB);
            b = FHH[((8+g)*2+0)*64+l];
            aNHA= MFMA16(h0hA,b,aNHA);aNHB= MFMA16(h0hB,b,aNHB);
            aNHA= MFMA16(h0lA,b,aNHA);aNHB= MFMA16(h0lB,b,aNHB);
            b = FHH[((8+g)*2+1)*64+l];
            aNHA= MFMA16(h1hA,b,aNHA);aNHB= MFMA16(h1hB,b,aNHB);
            aNHA= MFMA16(h1lA,b,aNHA);aNHB= MFMA16(h1lB,b,aNHB);
            // gates: group A
#pragma unroll
            for (int i = 0; i < 4; i++){
                float r_ = fsig(aRA[i]);
                float z_ = fsig(aZA[i]);
                float nn_ = ftanh(aNIA[i] + r_*aNHA[i]);
                float hn = nn_ + z_*(hprevA[u][i] - nn_);
                hprevA[u][i] = hn;
                int row = q*4 + i, col = g*16 + ln;
                int off = (col>>5)*512 + (16*((col&31)>>3) + row)*8 + (col&7);
                unsigned short hh_, hl_;
                tsplit(hn, hh_, hl_);
                hfh[1-p][off] = hh_;
                hfl[1-p][off] = hl_;
            }
            // gates: group B
#pragma unroll
            for (int i = 0; i < 4; i++){
                float r_ = fsig(aRB[i]);
                float z_ = fsig(aZB[i]);
                float nn_ = ftanh(aNIB[i] + r_*aNHB[i]);
                float hn = nn_ + z_*(hprevB[u][i] - nn_);
                hprevB[u][i] = hn;
                int row = q*4 + i, col = g*16 + ln;
                int off = 1024 + (col>>5)*512 + (16*((col&31)>>3) + row)*8 + (col&7);
                unsigned short hh_, hl_;
                tsplit(hn, hh_, hl_);
                hfh[1-p][off] = hh_;
                hfl[1-p][off] = hl_;
            }
        }
        __syncthreads();   // the ONLY barrier per step
        p ^= 1;
    }
    {
        v8s a0hA,a0lA,a1hA,a1lA, a0hB,a0lB,a1hB,a1lB;
        lrelu_resplit(*(const v8s*)&hfh[p][l*8],        *(const v8s*)&hfl[p][l*8],        a0hA, a0lA);
        lrelu_resplit(*(const v8s*)&hfh[p][512 + l*8],  *(const v8s*)&hfl[p][512 + l*8],  a1hA, a1lA);
        lrelu_resplit(*(const v8s*)&hfh[p][1024 + l*8], *(const v8s*)&hfl[p][1024 + l*8], a0hB, a0lB);
        lrelu_resplit(*(const v8s*)&hfh[p][1536 + l*8], *(const v8s*)&hfl[p][1536 + l*8], a1hB, a1lB);
#pragma unroll
        for (int u = 0; u < 2; u++){
            int nt = 2*w + u;
            float bb = bdyn[nt*16 + ln];
            v4f accA = {bb,bb,bb,bb}, accB = accA;
            v8s b;
            b = FDY[(nt*2+0)*64 + l];
            accA = MFMA16(a0hA,b,accA); accB = MFMA16(a0hB,b,accB);
            accA = MFMA16(a0lA,b,accA); accB = MFMA16(a0lB,b,accB);
            b = FDY[(nt*2+1)*64 + l];
            accA = MFMA16(a1hA,b,accA); accB = MFMA16(a1hB,b,accB);
            accA = MFMA16(a1lA,b,accA); accB = MFMA16(a1lB,b,accB);
#pragma unroll
            for (int i = 0; i < 4; i++){
                hist[(size_t)(gA*16 + q*4 + i)*64 + nt*16 + ln] = lrelu(accA[i]);
                if (bvalid)
                    hist[(size_t)(gB*16 + q*4 + i)*64 + nt*16 + ln] = lrelu(accB[i]);
            }
        }
    }
}

// ---------------- CGConv projections: MFMA (unchanged) ----------------
__global__ __launch_bounds__(256) void proj_mfma(
    const float* __restrict__ xin,
    const unsigned short* __restrict__ Bh, const unsigned short* __restrict__ Bl,
    float* __restrict__ Af, float* __restrict__ Bf,
    float* __restrict__ As, float* __restrict__ Bs)
{
    __shared__ float sx[64*68];
    const int tid = threadIdx.x;
    const int l = tid & 63;
    const int w = tid >> 6;
    const int ln = l & 15, q = l >> 4;
    const int n0 = blockIdx.x*64;

    for (int i=tid;i<64*16;i+=256){
        int nn = i>>4, f4 = i&15;
        float4 v = {0.f,0.f,0.f,0.f};
        if (n0+nn < NN) v = ((const float4*)(xin + (size_t)(n0+nn)*64))[f4];
        *(float4*)&sx[nn*68 + f4*4] = v;
    }
    __syncthreads();

    v8s ah0,al0,ah1,al1;
    cvt8(&sx[(w*16+ln)*68 +      q*8], ah0, al0);
    cvt8(&sx[(w*16+ln)*68 + 32 + q*8], ah1, al1);

    const v8s* FH = (const v8s*)Bh;
    const v8s* FL = (const v8s*)Bl;
#pragma unroll 1
    for (int nt=0; nt<16; nt++){
        v8s bh0 = FH[(nt*2+0)*64 + l], bl0 = FL[(nt*2+0)*64 + l];
        v8s bh1 = FH[(nt*2+1)*64 + l], bl1 = FL[(nt*2+1)*64 + l];
        v4f acc = {0.f,0.f,0.f,0.f};
        acc = MFMA16(ah0,bh0,acc); acc = MFMA16(al0,bh0,acc); acc = MFMA16(ah0,bl0,acc);
        acc = MFMA16(ah1,bh1,acc); acc = MFMA16(al1,bh1,acc); acc = MFMA16(ah1,bl1,acc);
        int d = nt >> 2, col = (nt&3)*16 + ln;
        float* op = (d==0) ? Af : (d==1) ? Bf : (d==2) ? As : Bs;
#pragma unroll
        for (int i=0;i<4;i++){
            int node = n0 + w*16 + q*4 + i;
            if (node < NN) op[(size_t)node*64 + col] = acc[i];
        }
    }
}

// ---------------- dst segment build: histogram + atomic alloc + scatter ----------------
__global__ void count_kernel(const int* __restrict__ ei, int* __restrict__ cnt){
    int e = blockIdx.x*256 + threadIdx.x;
    if (e < EE) atomicAdd(&cnt[ei[EE+e]], 1);
}

__global__ void alloc_kernel(const int* __restrict__ cnt, int* __restrict__ gtot,
                             int* __restrict__ off, int* __restrict__ cur){
    int n = blockIdx.x*256 + threadIdx.x;
    if (n >= NN) return;
    int c = cnt[n];
    int s = atomicAdd(gtot, c);
    off[n] = s;
    cur[n] = s;
}

// scatter + pre-gather (src, e0, e1) into ONE int4 record per edge
__global__ void scatter_kernel(const int* __restrict__ ei, const float* __restrict__ ea,
                               int* __restrict__ cur, int4* __restrict__ recS){
    int e = blockIdx.x*256 + threadIdx.x;
    if (e >= EE) return;
    int d = ei[EE+e];
    int p = atomicAdd(&cur[d], 1);
    int4 r;
    r.x = ei[e];
    r.y = __float_as_int(ea[2*(size_t)e]);
    r.z = __float_as_int(ea[2*(size_t)e+1]);
    r.w = 0;
    recS[p] = r;
}

// ---------------- CGConv aggregate (packed records) ----------------
__global__ __launch_bounds__(256) void cg_agg(
    const float* __restrict__ xin,
    const int4* __restrict__ recS,
    const int* __restrict__ off, const int* __restrict__ cnt,
    const float* __restrict__ Wf, const float* __restrict__ bf,
    const float* __restrict__ Ws, const float* __restrict__ bs,
    const float* __restrict__ Af, const float* __restrict__ Bf,
    const float* __restrict__ As, const float* __restrict__ Bs,
    const float* __restrict__ gamma, const float* __restrict__ beta,
    const float* __restrict__ mean, const float* __restrict__ var,
    float* __restrict__ outp)
{
    const int tid = threadIdx.x;
    const int c = tid & 63, wid = tid >> 6;
    const int n = blockIdx.x*4 + wid;
    if (n >= NN) return;

    const float wf0 = Wf[c*130+128], wf1 = Wf[c*130+129], bfc = bf[c];
    const float ws0 = Ws[c*130+128], ws1 = Ws[c*130+129], bsc = bs[c];
    const float afd = Af[(size_t)n*64+c] + bfc, asd = As[(size_t)n*64+c] + bsc;
    const float* Bfc = Bf + c;
    const float* Bsc = Bs + c;

    float acc = 0.f;
    int i = off[n];
    const int i1 = i + cnt[n];
#pragma unroll 1
    for (; i+1 < i1; i += 2){
        int4 r0 = recS[i], r1 = recS[i+1];
        float e00 = __int_as_float(r0.y), e01 = __int_as_float(r0.z);
        float e10 = __int_as_float(r1.y), e11 = __int_as_float(r1.z);
        float bf0v = Bfc[(size_t)r0.x*64], bs0v = Bsc[(size_t)r0.x*64];
        float bf1v = Bfc[(size_t)r1.x*64], bs1v = Bsc[(size_t)r1.x*64];
        float gf0 = afd + bf0v + wf0*e00 + wf1*e01;
        float gs0 = asd + bs0v + ws0*e00 + ws1*e01;
        float gf1 = afd + bf1v + wf0*e10 + wf1*e11;
        float gs1 = asd + bs1v + ws0*e10 + ws1*e11;
        acc += fsig(gf0)*fsoftplus(gs0);
        acc += fsig(gf1)*fsoftplus(gs1);
    }
    if (i < i1){
        int4 r0 = recS[i];
        float e00 = __int_as_float(r0.y), e01 = __int_as_float(r0.z);
        float gf = afd + Bfc[(size_t)r0.x*64] + wf0*e00 + wf1*e01;
        float gs = asd + Bsc[(size_t)r0.x*64] + ws0*e00 + ws1*e01;
        acc += fsig(gf)*fsoftplus(gs);
    }
    float bn = (acc - mean[c])*rsqrtf(var[c]+BN_EPS)*gamma[c] + beta[c];
    outp[(size_t)n*64+c] = xin[(size_t)n*64+c] + bn;
}

// ---------------- target gather + nbrs linear + concat (unchanged) ----------------
__global__ __launch_bounds__(256) void target_kernel(
    const float* __restrict__ hist, const float* __restrict__ f2,
    const int* __restrict__ tgt,
    const float* __restrict__ Wn, const float* __restrict__ bn_,
    float* __restrict__ enc)
{
    const int tid=threadIdx.x;
    const int c = tid&63, q = tid>>6;
    const int b = blockIdx.x*4 + q;
    if (b>=BB) return;
    const int n = tgt[b];
    float a = bn_[c];
#pragma unroll
    for (int k=0;k<ENC;k++) a += Wn[c*64+k]*f2[(size_t)n*64+k];
    enc[(size_t)b*128 + 64 + c] = lrelu(a);
    enc[(size_t)b*128 + c]      = hist[(size_t)n*64+c];
}

// ---------------- gi0 via MFMA (unchanged) ----------------
__global__ __launch_bounds__(512) void gi0_mfma(
    const float* __restrict__ enc,
    const unsigned short* __restrict__ GIh, const unsigned short* __restrict__ GIl,
    const float* __restrict__ bih0, const float* __restrict__ bhh0,
    float* __restrict__ gi0)
{
    __shared__ float senc[16*132];
    const int tid = threadIdx.x;
    const int l = tid & 63;
    const int w = tid >> 6;
    const int ln = l & 15, q = l >> 4;
    const int b0 = blockIdx.x*16;

    for (int i=tid;i<16*32;i+=512){
        int row = i>>5, f4 = i&31;
        *(float4*)&senc[row*132 + f4*4] = ((const float4*)(enc + (size_t)(b0+row)*128))[f4];
    }
    __syncthreads();

    v8s ah[4], al[4];
#pragma unroll
    for (int kb=0;kb<4;kb++) cvt8(&senc[ln*132 + kb*32 + q*8], ah[kb], al[kb]);

    const v8s* FH = (const v8s*)GIh;
    const v8s* FL = (const v8s*)GIl;
#pragma unroll
    for (int u=0;u<4;u++){
        int nt = w*4 + u;
        int col = nt*16 + ln;
        float bb = bih0[col] + bhh0[col];
        v4f acc = {bb,bb,bb,bb};
#pragma unroll
        for (int kb=0;kb<4;kb++){
            v8s bh = FH[(nt*4+kb)*64 + l];
            v8s bl = FL[(nt*4+kb)*64 + l];
            acc = MFMA16(ah[kb],bh,acc); acc = MFMA16(al[kb],bh,acc); acc = MFMA16(ah[kb],bl,acc);
        }
#pragma unroll
        for (int i=0;i<4;i++)
            gi0[(size_t)(b0 + q*4 + i)*512 + col] = acc[i];
    }
}

// ---------------- 2-layer LSTM decoder v7: ONE barrier/step (unchanged) ----------------
#define LMB 16
__global__ __launch_bounds__(512)
__attribute__((amdgpu_waves_per_eu(2,2)))
void lstm_mfma(
    const float* __restrict__ gi0,
    const unsigned short* __restrict__ B0h,
    const unsigned short* __restrict__ B1h,
    const float* __restrict__ bih1, const float* __restrict__ bhh1,
    const float* __restrict__ Wop, const float* __restrict__ bop,
    float* __restrict__ outp)
{
    __shared__ int4 sW0[32*4*64];                                // 131072 B
    __shared__ unsigned short h0hi[2][4*512], h0lo[2][4*512];    // 16384 B
    __shared__ unsigned short h1hi[2][4*512], h1lo[2][4*512];    // 16384 B
    const int tid = threadIdx.x;
    const int l = tid & 63;
    const int w = tid >> 6;
    const int c = l & 15;
    const int q = l >> 4;
    const int j = w*16 + c;
    const int b0 = blockIdx.x*LMB;

    {
        const int4* F0 = (const int4*)B0h;
        for (int i=tid;i<32*4*64;i+=512) sW0[i] = F0[i];
    }
    for (int i=tid;i<4*512;i+=512){
        h0hi[0][i]=0; h0lo[0][i]=0; h0hi[1][i]=0; h0lo[1][i]=0;
        h1hi[0][i]=0; h1lo[0][i]=0; h1hi[1][i]=0; h1lo[1][i]=0;
    }

    int4 W1r[32];
    {
        const int4* F1 = (const int4*)B1h;
#pragma unroll
        for (int g=0;g<4;g++)
#pragma unroll
            for (int kb=0;kb<8;kb++) W1r[g*8+kb] = F1[((g*8+w)*8 + kb)*64 + l];
#pragma unroll
        for (int i=0;i<32;i++)
            asm volatile("" : "+v"(W1r[i].x), "+v"(W1r[i].y), "+v"(W1r[i].z), "+v"(W1r[i].w));
    }

    float rgi[4][4];
#pragma unroll
    for (int g=0;g<4;g++)
#pragma unroll
        for (int i=0;i<4;i++)
            rgi[g][i] = gi0[(size_t)(b0 + q*4 + i)*512 + g*128 + j];

    float b1[4];
#pragma unroll
    for (int g=0;g<4;g++) b1[g] = bih1[g*128+j] + bhh1[g*128+j];
    float c0[4] = {0,0,0,0}, c1[4] = {0,0,0,0};
    const float wop0 = Wop[j], wop1 = Wop[128 + j];
    const float bo0 = bop[0], bo1 = bop[1];
    const int kbw = j>>5, qw = (j>>3)&3, jw = j&7;
    __syncthreads();

    int p = 0;
#pragma unroll 1
    for (int t=0;t<OUTL;t++){
        // ---- layer 0: read h0[p], write h0[1-p]; dual hi/lo accumulators ----
        v4f aH[4], aL[4];
#pragma unroll
        for (int g=0;g<4;g++){
            v4f t4 = {rgi[g][0], rgi[g][1], rgi[g][2], rgi[g][3]};
            aH[g] = t4;
            v4f z = {0.f,0.f,0.f,0.f};
            aL[g] = z;
        }
#pragma unroll
        for (int kb=0;kb<4;kb++){
            v8s ah = *(const v8s*)&h0hi[p][kb*512 + l*8];
            v8s al = *(const v8s*)&h0lo[p][kb*512 + l*8];
#pragma unroll
            for (int g=0;g<4;g++){
                v8s bfr = as_v8s(sW0[((g*8+w)*4 + kb)*64 + l]);
                aH[g] = MFMA16(ah, bfr, aH[g]);
                aL[g] = MFMA16(al, bfr, aL[g]);
            }
        }
#pragma unroll
        for (int i=0;i<4;i++){
            float gi_ = aH[0][i]+aL[0][i], gf_ = aH[1][i]+aL[1][i];
            float gg_ = aH[2][i]+aL[2][i], go_ = aH[3][i]+aL[3][i];
            c0[i] = fsig(gf_)*c0[i] + fsig(gi_)*ftanh(gg_);
            float hn = fsig(go_)*ftanh(c0[i]);
            int off = kbw*512 + (qw*16 + q*4 + i)*8 + jw;
            unsigned short h = f2bf(hn);
            h0hi[1-p][off] = h;
            h0lo[1-p][off] = f2bf(hn - bf2f(h));
        }
        __syncthreads();   // B1: the ONLY barrier per step

        // ---- layer 1: read h0[1-p] + h1[p], write h1[1-p] ----
        v4f bH[4], bL[4];
#pragma unroll
        for (int g=0;g<4;g++){
            v4f t4={b1[g],b1[g],b1[g],b1[g]}; bH[g]=t4;
            v4f z={0.f,0.f,0.f,0.f}; bL[g]=z;
        }
#pragma unroll
        for (int kb=0;kb<8;kb++){
            const unsigned short* hb = (kb<4) ? h0hi[1-p] : h1hi[p];
            const unsigned short* lb = (kb<4) ? h0lo[1-p] : h1lo[p];
            int kk = kb & 3;
            v8s ah = *(const v8s*)&hb[kk*512 + l*8];
            v8s al = *(const v8s*)&lb[kk*512 + l*8];
#pragma unroll
            for (int g=0;g<4;g++){
                bH[g] = MFMA16(ah, as_v8s(W1r[g*8+kb]), bH[g]);
                bL[g] = MFMA16(al, as_v8s(W1r[g*8+kb]), bL[g]);
            }
        }
        float h1new[4];
#pragma unroll
        for (int i=0;i<4;i++){
            float gi_ = bH[0][i]+bL[0][i], gf_ = bH[1][i]+bL[1][i];
            float gg_ = bH[2][i]+bL[2][i], go_ = bH[3][i]+bL[3][i];
            c1[i] = fsig(gf_)*c1[i] + fsig(gi_)*ftanh(gg_);
            h1new[i] = fsig(go_)*ftanh(c1[i]);
            int off = kbw*512 + (qw*16 + q*4 + i)*8 + jw;
            unsigned short h = f2bf(h1new[i]);
            h1hi[1-p][off] = h;
            h1lo[1-p][off] = f2bf(h1new[i] - bf2f(h));
        }

        // ---- out-proj: register partials, wave shuffle-reduce, atomicAdd ----
        {
            float v0[4], v1[4];
#pragma unroll
            for (int i=0;i<4;i++){ v0[i] = h1new[i]*wop0; v1[i] = h1new[i]*wop1; }
#pragma unroll
            for (int m=1;m<16;m<<=1){
#pragma unroll
                for (int i=0;i<4;i++){
                    v0[i] += __shfl_xor(v0[i], m);
                    v1[i] += __shfl_xor(v1[i], m);
                }
            }
            if (c == 0){
                if (w == 0){
#pragma unroll
                    for (int i=0;i<4;i++){ v0[i] += bo0; v1[i] += bo1; }
                }
#pragma unroll
                for (int i=0;i<4;i++){
                    size_t base = (size_t)(b0 + q*4 + i)*(OUTL*2) + t*2;
                    atomicAdd(&outp[base    ], v0[i]);
                    atomicAdd(&outp[base + 1], v1[i]);
                }
            }
        }
        p ^= 1;
    }
}

extern "C" void kernel_launch(void* const* d_in, const int* in_sizes, int n_in,
                              void* d_out, int out_size, void* d_ws, size_t ws_size,
                              hipStream_t stream)
{
    const float* x    = (const float*)d_in[0];
    const int*   ei   = (const int*)d_in[1];
    const float* ea   = (const float*)d_in[2];
    const int*   tgt  = (const int*)d_in[3];
    const float* Wip  = (const float*)d_in[4];
    const float* bip  = (const float*)d_in[5];
    const float* gWih = (const float*)d_in[6];
    const float* gWhh = (const float*)d_in[7];
    const float* gbih = (const float*)d_in[8];
    const float* gbhh = (const float*)d_in[9];
    const float* Wdyn = (const float*)d_in[10];
    const float* bdyn = (const float*)d_in[11];
    const float* c1Wf=(const float*)d_in[12]; const float* c1bf=(const float*)d_in[13];
    const float* c1Ws=(const float*)d_in[14]; const float* c1bs=(const float*)d_in[15];
    const float* c1g =(const float*)d_in[16]; const float* c1b =(const float*)d_in[17];
    const float* c1m =(const float*)d_in[18]; const float* c1v =(const float*)d_in[19];
    const float* c2Wf=(const float*)d_in[20]; const float* c2bf=(const float*)d_in[21];
    const float* c2Ws=(const float*)d_in[22]; const float* c2bs=(const float*)d_in[23];
    const float* c2g =(const float*)d_in[24]; const float* c2b =(const float*)d_in[25];
    const float* c2m =(const float*)d_in[26]; const float* c2v =(const float*)d_in[27];
    const float* Wn  =(const float*)d_in[28]; const float* bn_ =(const float*)d_in[29];
    const float* l0Wih=(const float*)d_in[30]; const float* l0Whh=(const float*)d_in[31];
    const float* l0bih=(const float*)d_in[32]; const float* l0bhh=(const float*)d_in[33];
    const float* l1Wih=(const float*)d_in[34]; const float* l1Whh=(const float*)d_in[35];
    const float* l1bih=(const float*)d_in[36]; const float* l1bhh=(const float*)d_in[37];
    const float* Wop =(const float*)d_in[38]; const float* bop=(const float*)d_in[39];

    float* ws = (float*)d_ws;
    size_t o = 0;
    float* hist = ws + o; o += (size_t)NN*ENC;
    float* f1   = ws + o; o += (size_t)NN*ENC;
    float* f2   = ws + o; o += (size_t)NN*ENC;
    float* Af   = ws + o; o += (size_t)NN*ENC;
    float* Bf   = ws + o; o += (size_t)NN*ENC;
    float* As   = ws + o; o += (size_t)NN*ENC;
    float* Bs   = ws + o; o += (size_t)NN*ENC;
    float* enc  = ws + o; o += (size_t)BB*2*ENC;
    float* gi0  = ws + o; o += (size_t)BB*4*DEC;
    unsigned short* pWih  = (unsigned short*)(ws + o); o += (size_t)12*64*8/2;
    unsigned short* pWhh  = (unsigned short*)(ws + o); o += (size_t)24*64*8/2;
    unsigned short* pWdyn = (unsigned short*)(ws + o); o += (size_t)8*64*8/2;
    unsigned short* B0h = (unsigned short*)(ws + o); o += (size_t)32*4*64*8/2;
    unsigned short* B1h = (unsigned short*)(ws + o); o += (size_t)32*8*64*8/2;
    unsigned short* P1h = (unsigned short*)(ws + o); o += (size_t)2048*8/2;
    unsigned short* P1l = (unsigned short*)(ws + o); o += (size_t)2048*8/2;
    unsigned short* P2h = (unsigned short*)(ws + o); o += (size_t)2048*8/2;
    unsigned short* P2l = (unsigned short*)(ws + o); o += (size_t)2048*8/2;
    unsigned short* GIh = (unsigned short*)(ws + o); o += (size_t)8192*8/2;
    unsigned short* GIl = (unsigned short*)(ws + o); o += (size_t)8192*8/2;
    int* cnt    = (int*)(ws + o); o += NN;
    int* offv   = (int*)(ws + o); o += NN+1;
    int* curv   = (int*)(ws + o); o += NN;
    int* gtot   = (int*)(ws + o); o += 1;
    o = (o + 3) & ~(size_t)3;               // align to 16B for int4 records
    int4* recS  = (int4*)(ws + o); o += (size_t)4*EE;

    // --- all weight prep + cnt/gtot zero in one dispatch ---
    pack_all<<<(PACK_TOTAL+255)/256, 256, 0, stream>>>(
        gWih, gWhh, Wdyn, l0Whh, l1Wih, l1Whh, l0Wih,
        c1Wf, c1Ws, c2Wf, c2Ws,
        pWih, pWhh, pWdyn, B0h, B1h, P1h, P1l, P2h, P2l, GIh, GIl, cnt, gtot);

    // --- zero output (lstm accumulates via atomics) ---
    (void)hipMemsetAsync(d_out, 0, (size_t)out_size*sizeof(float), stream);

    // --- dst segment build (order-free atomic allocation) ---
    count_kernel<<<(EE+255)/256, 256, 0, stream>>>(ei, cnt);
    alloc_kernel<<<(NN+255)/256, 256, 0, stream>>>(cnt, gtot, offv, curv);
    scatter_kernel<<<(EE+255)/256, 256, 0, stream>>>(ei, ea, curv, recS);

    // --- history encoder (MFMA, 2 node-groups per block) ---
    encoder_mfma<<<(NN/16 + 1)/2, 128, 0, stream>>>(x, Wip, bip, pWih, pWhh, gbih, gbhh, pWdyn, bdyn, hist);

    // --- CGConv 1 ---
    proj_mfma<<<(NN+63)/64, 256, 0, stream>>>(hist, P1h, P1l, Af,Bf,As,Bs);
    cg_agg<<<(NN+3)/4, 256, 0, stream>>>(hist, recS, offv, cnt,
                                         c1Wf,c1bf,c1Ws,c1bs, Af,Bf,As,Bs,
                                         c1g,c1b,c1m,c1v, f1);

    // --- CGConv 2 ---
    proj_mfma<<<(NN+63)/64, 256, 0, stream>>>(f1, P2h, P2l, Af,Bf,As,Bs);
    cg_agg<<<(NN+3)/4, 256, 0, stream>>>(f1, recS, offv, cnt,
                                         c2Wf,c2bf,c2Ws,c2bs, Af,Bf,As,Bs,
                                         c2g,c2b,c2m,c2v, f2);

    // --- target encoding ---
    target_kernel<<<(BB+3)/4, 256, 0, stream>>>(hist, f2, tgt, Wn, bn_, enc);

    // --- LSTM decoder prep (MFMA gi0) ---
    gi0_mfma<<<BB/16, 512, 0, stream>>>(enc, GIh, GIl, l0bih, l0bhh, gi0);

    // --- LSTM decoder (1-barrier t-loop) ---
    lstm_mfma<<<BB/LMB, 512, 0, stream>>>(gi0, B0h, B1h,
                                          l1bih, l1bhh, Wop, bop, (float*)d_out);
}

// Round 4
// 615.169 us; speedup vs baseline: 1.0222x; 1.0222x over previous
//
#include <hip/hip_runtime.h>
#include <math.h>

#define NN   50000
#define TT   16
#define EE   800000
#define BB   2000
#define EMBD 32
#define ENC  64
#define DEC  128
#define OUTL 25
#define BN_EPS 1e-5f

typedef short v8s __attribute__((ext_vector_type(8)));
typedef float v4f __attribute__((ext_vector_type(4)));
#define MFMA16(a,b,c) __builtin_amdgcn_mfma_f32_16x16x32_bf16((a),(b),(c),0,0,0)

__device__ __forceinline__ float lrelu(float v){ return v >= 0.f ? v : 0.1f*v; }
__device__ __forceinline__ float fsig(float v){ return __builtin_amdgcn_rcpf(1.f + __expf(-v)); }
__device__ __forceinline__ float ftanh(float v){ return 2.f*__builtin_amdgcn_rcpf(1.f + __expf(-2.f*v)) - 1.f; }
__device__ __forceinline__ float fsoftplus(float v){
    return v > 15.f ? v : __logf(1.f + __expf(v));
}
__device__ __forceinline__ float hsum(float4 a){ return (a.x+a.y)+(a.z+a.w); }

__device__ __forceinline__ unsigned short f2bf(float f){
    unsigned u = __float_as_uint(f);
    u = u + 0x7FFFu + ((u>>16)&1u);
    return (unsigned short)(u>>16);
}
__device__ __forceinline__ float bf2f(unsigned short s){ return __uint_as_float(((unsigned)s)<<16); }

// truncation-based hi/lo split (R12): hi = truncated bf16, lo = bf16 of the
// exact residual; ~4 VALU ops vs ~8 for the RNE pair, same net precision.
__device__ __forceinline__ void tsplit(float v, unsigned short& hi, unsigned short& lo){
    unsigned u = __float_as_uint(v);
    hi = (unsigned short)(u >> 16);
    float r = v - __uint_as_float(u & 0xFFFF0000u);
    lo = (unsigned short)(__float_as_uint(r) >> 16);
}

__device__ __forceinline__ v8s as_v8s(int4 v){
    union { int4 i; v8s s; } u; u.i = v; return u.s;
}

__device__ __forceinline__ void cvt8(const float* p, v8s& hi, v8s& lo){
    float4 a0 = *(const float4*)p;
    float4 a1 = *(const float4*)(p+4);
    float av[8] = {a0.x,a0.y,a0.z,a0.w,a1.x,a1.y,a1.z,a1.w};
#pragma unroll
    for (int j=0;j<8;j++){
        unsigned short h = f2bf(av[j]);
        hi[j] = (short)h;
        lo[j] = (short)f2bf(av[j] - bf2f(h));
    }
}
// reconstruct hi+lo, lrelu, re-split
__device__ __forceinline__ void lrelu_resplit(v8s hh, v8s hl, v8s& oh, v8s& ol){
#pragma unroll
    for (int j=0;j<8;j++){
        float v = bf2f((unsigned short)hh[j]) + bf2f((unsigned short)hl[j]);
        float a = lrelu(v);
        unsigned short h = f2bf(a);
        oh[j] = (short)h;
        ol[j] = (short)f2bf(a - bf2f(h));
    }
}

// ---------------- fused packing helpers ----------------
__device__ __forceinline__ void pf_item(const float* W, int K, int KB, int i,
                                        unsigned short* out){
    int l = i & 63, fb = i >> 6;
    int kb = fb % KB, nt = fb / KB;
    int n = nt*16 + (l&15);
    int k0 = kb*32 + ((l>>4)*8);
#pragma unroll
    for (int j=0;j<8;j++) out[i*8+j] = f2bf(W[(size_t)n*K + k0 + j]);
}
__device__ __forceinline__ void phl_item(const float* W, int K, int KB, int i,
                                         unsigned short* hi, unsigned short* lo){
    int l = i & 63, fb = i >> 6;
    int kb = fb % KB, nt = fb / KB;
    int n = nt*16 + (l&15);
    int k0 = kb*32 + ((l>>4)*8);
#pragma unroll
    for (int j=0;j<8;j++){
        float v = W[(size_t)n*K + k0 + j];
        unsigned short h = f2bf(v);
        hi[i*8+j] = h;
        lo[i*8+j] = f2bf(v - bf2f(h));
    }
}
__device__ __forceinline__ void pcat_item(const float* Wa, const float* Wb,
                                          int K1, int K, int KB, int i,
                                          unsigned short* out){
    int l = i & 63, fb = i >> 6;
    int kb = fb % KB, nt = fb / KB;
    int n = nt*16 + (l&15);
    int k0 = kb*32 + ((l>>4)*8);
#pragma unroll
    for (int j=0;j<8;j++){
        int k = k0 + j;
        float v = (k < K1) ? Wa[(size_t)n*K1 + k] : Wb[(size_t)n*(K-K1) + (k-K1)];
        out[i*8+j] = f2bf(v);
    }
}
__device__ __forceinline__ void pproj_item(const float* Wf, const float* Ws, int i,
                                           unsigned short* hi, unsigned short* lo){
    int l = i & 63, fb = i >> 6;
    int kb = fb & 1, nt = fb >> 1;
    int n = nt*16 + (l&15);
    int d = n >> 6, c = n & 63;
    const float* W = (d < 2) ? Wf : Ws;
    int k0 = (d&1)*64 + kb*32 + ((l>>4)*8);
#pragma unroll
    for (int j=0;j<8;j++){
        float v = W[c*130 + k0 + j];
        unsigned short h = f2bf(v);
        hi[i*8+j] = h;
        lo[i*8+j] = f2bf(v - bf2f(h));
    }
}

// ---------------- all weight prep in ONE dispatch ----------------
__global__ void pack_all(
    const float* __restrict__ gWih, const float* __restrict__ gWhh,
    const float* __restrict__ Wdyn,
    const float* __restrict__ l0Whh, const float* __restrict__ l1Wih,
    const float* __restrict__ l1Whh, const float* __restrict__ l0Wih,
    const float* __restrict__ c1Wf, const float* __restrict__ c1Ws,
    const float* __restrict__ c2Wf, const float* __restrict__ c2Ws,
    unsigned short* __restrict__ pWih, unsigned short* __restrict__ pWhh,
    unsigned short* __restrict__ pWdyn,
    unsigned short* __restrict__ B0h, unsigned short* __restrict__ B1h,
    unsigned short* __restrict__ P1h, unsigned short* __restrict__ P1l,
    unsigned short* __restrict__ P2h, unsigned short* __restrict__ P2l,
    unsigned short* __restrict__ GIh, unsigned short* __restrict__ GIl,
    int* __restrict__ cnt, int* __restrict__ gtot)
{
    int i = blockIdx.x*256 + threadIdx.x;
    if (i < 768){ pf_item(gWih, 32, 1, i, pWih); return; }   i -= 768;
    if (i < 1536){ pf_item(gWhh, 64, 2, i, pWhh); return; }  i -= 1536;
    if (i < 512){ pf_item(Wdyn, 64, 2, i, pWdyn); return; }  i -= 512;
    if (i < 8192){ pcat_item(l0Whh, l0Whh, 128, 128, 4, i, B0h); return; } i -= 8192;
    if (i < 16384){ pcat_item(l1Wih, l1Whh, 128, 256, 8, i, B1h); return; } i -= 16384;
    if (i < 2048){ pproj_item(c1Wf, c1Ws, i, P1h, P1l); return; } i -= 2048;
    if (i < 2048){ pproj_item(c2Wf, c2Ws, i, P2h, P2l); return; } i -= 2048;
    if (i < 8192){ phl_item(l0Wih, 128, 4, i, GIh, GIl); return; } i -= 8192;
    if (i < NN){ cnt[i] = 0; return; } i -= NN;
    if (i < 1){ gtot[0] = 0; return; }
}
#define PACK_TOTAL (768+1536+512+8192+16384+2048+2048+8192+NN+1)

// ---------------- GRU encoder v8: 4 light waves + LDS XOR swizzle ----------------
// R15 post-mortems: v5 (1 fat wave) and v7 (2 problems/wave) both REGRESSED;
// v6 (2 waves, 107us) wins -> direction is MORE, LIGHTER waves. Also R2's
// counters showed 3.95M LDS bank conflicts: the h-frag ds_write_b16 banks are
// 16(q&1)+4i+((ln&7)>>1) for fixed gate iter i -> 8 banks/64 lanes = 8-way.
// v8:
//  - 4 waves x 1 g-tile each (per-wave: 18 MFMA, 4 gate values, 8 writes);
//    VGPR drops -> more waves/SIMD to hide MFMA->gate latency.
//  - XOR swizzle off ^= ((row>>1)&7)<<3 on h-frag LDS (bijective; write banks
//    -> 16-distinct/2-way = free; reads l*8 w/ key (l>>1)&7 stay conflict-free).
//  - reg e-frags, dbuf h, ONE barrier/step, tsplit: unchanged from v6.
__global__ __launch_bounds__(256) void encoder_mfma(
    const float* __restrict__ x,
    const float* __restrict__ Wip, const float* __restrict__ bip,
    const unsigned short* __restrict__ pWih,
    const unsigned short* __restrict__ pWhh,
    const float* __restrict__ bih, const float* __restrict__ bhh,
    const unsigned short* __restrict__ pWdyn,
    const float* __restrict__ bdyn,
    float* __restrict__ hist)
{
    __shared__ float sxt[512];                                 // x transposed [t][m][c]
    __shared__ unsigned short hfh[2][1024], hfl[2][1024];      // dbuf h A-frags (swizzled)
    const int tid = threadIdx.x;
    const int l   = tid & 63;
    const int w   = tid >> 6;          // wave owns g-tile w (output cols w*16..w*16+15)
    const int ln  = l & 15, q = l >> 4;
    const int blk = blockIdx.x;
    const int rsw = ((l>>1)&7)<<3;     // read swizzle key for this lane's frag row

    for (int idx = tid; idx < 512; idx += 256){
        int m = idx >> 5, r = idx & 31;                        // r = t*2 + c
        sxt[(r>>1)*32 + m*2 + (r&1)] = x[(size_t)blk*512 + idx];
    }
    for (int i = tid; i < 1024; i += 256){
        hfh[0][i]=0; hfl[0][i]=0; hfh[1][i]=0; hfl[1][i]=0;
    }

    // per-lane input-projection weights for k = q*8+j (same in all waves)
    float w0[8], w1[8], bk[8];
#pragma unroll
    for (int j = 0; j < 8; j++){
        int k = q*8 + j;
        w0[j] = Wip[2*k]; w1[j] = Wip[2*k+1]; bk[j] = bip[k];
    }

    const int c = w*16 + ln;
    const float bR  = bih[c]       + bhh[c];
    const float bZ  = bih[64 + c]  + bhh[64 + c];
    const float bNI = bih[128 + c];
    const float bNH = bhh[128 + c];
    float hprev[4] = {0.f,0.f,0.f,0.f};

    const v8s* FIH = (const v8s*)pWih;
    const v8s* FHH = (const v8s*)pWhh;
    const v8s* FDY = (const v8s*)pWdyn;
    // write-address constants: col = c fixed per thread
    const int wbase = (c>>5)*512 + (16*((c&31)>>3))*8 + (c&7);
    __syncthreads();

    int p = 0;
#pragma unroll 1
    for (int t = 0; t < TT; t++){
        // ---- e A-frag in registers ----
        float2 xv = *(const float2*)&sxt[t*32 + ln*2];
        v8s eh, el;
#pragma unroll
        for (int j = 0; j < 8; j++){
            float e = lrelu(w0[j]*xv.x + w1[j]*xv.y + bk[j]);
            unsigned short h_, l_;
            tsplit(e, h_, l_);
            eh[j] = (short)h_; el[j] = (short)l_;
        }
        v8s h0h = *(const v8s*)&hfh[p][(l*8) ^ rsw];
        v8s h0l = *(const v8s*)&hfl[p][(l*8) ^ rsw];
        v8s h1h = *(const v8s*)&hfh[p][512 + ((l*8) ^ rsw)];
        v8s h1l = *(const v8s*)&hfl[p][512 + ((l*8) ^ rsw)];

        v4f aR = {bR,bR,bR,bR};
        v4f aZ = {bZ,bZ,bZ,bZ};
        v4f aNI= {bNI,bNI,bNI,bNI};
        v4f aNH= {bNH,bNH,bNH,bNH};
        v8s b;
        b = FIH[(w   )*64 + l];    aR = MFMA16(eh,b,aR);  aR = MFMA16(el,b,aR);
        b = FHH[(w*2+0)*64+l];     aR = MFMA16(h0h,b,aR); aR = MFMA16(h0l,b,aR);
        b = FHH[(w*2+1)*64+l];     aR = MFMA16(h1h,b,aR); aR = MFMA16(h1l,b,aR);
        b = FIH[(4+w )*64 + l];    aZ = MFMA16(eh,b,aZ);  aZ = MFMA16(el,b,aZ);
        b = FHH[((4+w)*2+0)*64+l]; aZ = MFMA16(h0h,b,aZ); aZ = MFMA16(h0l,b,aZ);
        b = FHH[((4+w)*2+1)*64+l]; aZ = MFMA16(h1h,b,aZ); aZ = MFMA16(h1l,b,aZ);
        b = FIH[(8+w )*64 + l];    aNI= MFMA16(eh,b,aNI); aNI= MFMA16(el,b,aNI);
        b = FHH[((8+w)*2+0)*64+l]; aNH= MFMA16(h0h,b,aNH);aNH= MFMA16(h0l,b,aNH);
        b = FHH[((8+w)*2+1)*64+l]; aNH= MFMA16(h1h,b,aNH);aNH= MFMA16(h1l,b,aNH);

#pragma unroll
        for (int i = 0; i < 4; i++){
            float r_ = fsig(aR[i]);
            float z_ = fsig(aZ[i]);
            float nn_ = ftanh(aNI[i] + r_*aNH[i]);
            float hn = nn_ + z_*(hprev[i] - nn_);
            hprev[i] = hn;
            int row = q*4 + i;
            int off = (wbase + row*8) ^ ((((row)>>1)&7)<<3);
            unsigned short hh_, hl_;
            tsplit(hn, hh_, hl_);
            hfh[1-p][off] = hh_;
            hfl[1-p][off] = hl_;
        }
        __syncthreads();   // the ONLY barrier per step
        p ^= 1;
    }
    {
        v8s a0h,a0l,a1h,a1l;
        lrelu_resplit(*(const v8s*)&hfh[p][(l*8) ^ rsw],
                      *(const v8s*)&hfl[p][(l*8) ^ rsw],       a0h, a0l);
        lrelu_resplit(*(const v8s*)&hfh[p][512 + ((l*8) ^ rsw)],
                      *(const v8s*)&hfl[p][512 + ((l*8) ^ rsw)], a1h, a1l);
        const int nt = w;
        float bb = bdyn[nt*16 + ln];
        v4f acc = {bb,bb,bb,bb};
        v8s b;
        b = FDY[(nt*2+0)*64 + l]; acc = MFMA16(a0h,b,acc); acc = MFMA16(a0l,b,acc);
        b = FDY[(nt*2+1)*64 + l]; acc = MFMA16(a1h,b,acc); acc = MFMA16(a1l,b,acc);
#pragma unroll
        for (int i = 0; i < 4; i++){
            hist[(size_t)(blk*16 + q*4 + i)*64 + nt*16 + ln] = lrelu(acc[i]);
        }
    }
}

// ---------------- CGConv projections: MFMA (unchanged) ----------------
__global__ __launch_bounds__(256) void proj_mfma(
    const float* __restrict__ xin,
    const unsigned short* __restrict__ Bh, const unsigned short* __restrict__ Bl,
    float* __restrict__ Af, float* __restrict__ Bf,
    float* __restrict__ As, float* __restrict__ Bs)
{
    __shared__ float sx[64*68];
    const int tid = threadIdx.x;
    const int l = tid & 63;
    const int w = tid >> 6;
    const int ln = l & 15, q = l >> 4;
    const int n0 = blockIdx.x*64;

    for (int i=tid;i<64*16;i+=256){
        int nn = i>>4, f4 = i&15;
        float4 v = {0.f,0.f,0.f,0.f};
        if (n0+nn < NN) v = ((const float4*)(xin + (size_t)(n0+nn)*64))[f4];
        *(float4*)&sx[nn*68 + f4*4] = v;
    }
    __syncthreads();

    v8s ah0,al0,ah1,al1;
    cvt8(&sx[(w*16+ln)*68 +      q*8], ah0, al0);
    cvt8(&sx[(w*16+ln)*68 + 32 + q*8], ah1, al1);

    const v8s* FH = (const v8s*)Bh;
    const v8s* FL = (const v8s*)Bl;
#pragma unroll 1
    for (int nt=0; nt<16; nt++){
        v8s bh0 = FH[(nt*2+0)*64 + l], bl0 = FL[(nt*2+0)*64 + l];
        v8s bh1 = FH[(nt*2+1)*64 + l], bl1 = FL[(nt*2+1)*64 + l];
        v4f acc = {0.f,0.f,0.f,0.f};
        acc = MFMA16(ah0,bh0,acc); acc = MFMA16(al0,bh0,acc); acc = MFMA16(ah0,bl0,acc);
        acc = MFMA16(ah1,bh1,acc); acc = MFMA16(al1,bh1,acc); acc = MFMA16(ah1,bl1,acc);
        int d = nt >> 2, col = (nt&3)*16 + ln;
        float* op = (d==0) ? Af : (d==1) ? Bf : (d==2) ? As : Bs;
#pragma unroll
        for (int i=0;i<4;i++){
            int node = n0 + w*16 + q*4 + i;
            if (node < NN) op[(size_t)node*64 + col] = acc[i];
        }
    }
}

// ---------------- dst segment build: histogram + atomic alloc + scatter ----------------
__global__ void count_kernel(const int* __restrict__ ei, int* __restrict__ cnt){
    int e = blockIdx.x*256 + threadIdx.x;
    if (e < EE) atomicAdd(&cnt[ei[EE+e]], 1);
}

__global__ void alloc_kernel(const int* __restrict__ cnt, int* __restrict__ gtot,
                             int* __restrict__ off, int* __restrict__ cur){
    int n = blockIdx.x*256 + threadIdx.x;
    if (n >= NN) return;
    int c = cnt[n];
    int s = atomicAdd(gtot, c);
    off[n] = s;
    cur[n] = s;
}

// scatter + pre-gather (src, e0, e1) into ONE int4 record per edge
__global__ void scatter_kernel(const int* __restrict__ ei, const float* __restrict__ ea,
                               int* __restrict__ cur, int4* __restrict__ recS){
    int e = blockIdx.x*256 + threadIdx.x;
    if (e >= EE) return;
    int d = ei[EE+e];
    int p = atomicAdd(&cur[d], 1);
    int4 r;
    r.x = ei[e];
    r.y = __float_as_int(ea[2*(size_t)e]);
    r.z = __float_as_int(ea[2*(size_t)e+1]);
    r.w = 0;
    recS[p] = r;
}

// ---------------- CGConv aggregate (packed records) ----------------
__global__ __launch_bounds__(256) void cg_agg(
    const float* __restrict__ xin,
    const int4* __restrict__ recS,
    const int* __restrict__ off, const int* __restrict__ cnt,
    const float* __restrict__ Wf, const float* __restrict__ bf,
    const float* __restrict__ Ws, const float* __restrict__ bs,
    const float* __restrict__ Af, const float* __restrict__ Bf,
    const float* __restrict__ As, const float* __restrict__ Bs,
    const float* __restrict__ gamma, const float* __restrict__ beta,
    const float* __restrict__ mean, const float* __restrict__ var,
    float* __restrict__ outp)
{
    const int tid = threadIdx.x;
    const int c = tid & 63, wid = tid >> 6;
    const int n = blockIdx.x*4 + wid;
    if (n >= NN) return;

    const float wf0 = Wf[c*130+128], wf1 = Wf[c*130+129], bfc = bf[c];
    const float ws0 = Ws[c*130+128], ws1 = Ws[c*130+129], bsc = bs[c];
    const float afd = Af[(size_t)n*64+c] + bfc, asd = As[(size_t)n*64+c] + bsc;
    const float* Bfc = Bf + c;
    const float* Bsc = Bs + c;

    float acc = 0.f;
    int i = off[n];
    const int i1 = i + cnt[n];
#pragma unroll 1
    for (; i+1 < i1; i += 2){
        int4 r0 = recS[i], r1 = recS[i+1];
        float e00 = __int_as_float(r0.y), e01 = __int_as_float(r0.z);
        float e10 = __int_as_float(r1.y), e11 = __int_as_float(r1.z);
        float bf0v = Bfc[(size_t)r0.x*64], bs0v = Bsc[(size_t)r0.x*64];
        float bf1v = Bfc[(size_t)r1.x*64], bs1v = Bsc[(size_t)r1.x*64];
        float gf0 = afd + bf0v + wf0*e00 + wf1*e01;
        float gs0 = asd + bs0v + ws0*e00 + ws1*e01;
        float gf1 = afd + bf1v + wf0*e10 + wf1*e11;
        float gs1 = asd + bs1v + ws0*e10 + ws1*e11;
        acc += fsig(gf0)*fsoftplus(gs0);
        acc += fsig(gf1)*fsoftplus(gs1);
    }
    if (i < i1){
        int4 r0 = recS[i];
        float e00 = __int_as_float(r0.y), e01 = __int_as_float(r0.z);
        float gf = afd + Bfc[(size_t)r0.x*64] + wf0*e00 + wf1*e01;
        float gs = asd + Bsc[(size_t)r0.x*64] + ws0*e00 + ws1*e01;
        acc += fsig(gf)*fsoftplus(gs);
    }
    float bn = (acc - mean[c])*rsqrtf(var[c]+BN_EPS)*gamma[c] + beta[c];
    outp[(size_t)n*64+c] = xin[(size_t)n*64+c] + bn;
}

// ---------------- target gather + nbrs linear + concat (unchanged) ----------------
__global__ __launch_bounds__(256) void target_kernel(
    const float* __restrict__ hist, const float* __restrict__ f2,
    const int* __restrict__ tgt,
    const float* __restrict__ Wn, const float* __restrict__ bn_,
    float* __restrict__ enc)
{
    const int tid=threadIdx.x;
    const int c = tid&63, q = tid>>6;
    const int b = blockIdx.x*4 + q;
    if (b>=BB) return;
    const int n = tgt[b];
    float a = bn_[c];
#pragma unroll
    for (int k=0;k<ENC;k++) a += Wn[c*64+k]*f2[(size_t)n*64+k];
    enc[(size_t)b*128 + 64 + c] = lrelu(a);
    enc[(size_t)b*128 + c]      = hist[(size_t)n*64+c];
}

// ---------------- gi0 via MFMA (unchanged) ----------------
__global__ __launch_bounds__(512) void gi0_mfma(
    const float* __restrict__ enc,
    const unsigned short* __restrict__ GIh, const unsigned short* __restrict__ GIl,
    const float* __restrict__ bih0, const float* __restrict__ bhh0,
    float* __restrict__ gi0)
{
    __shared__ float senc[16*132];
    const int tid = threadIdx.x;
    const int l = tid & 63;
    const int w = tid >> 6;
    const int ln = l & 15, q = l >> 4;
    const int b0 = blockIdx.x*16;

    for (int i=tid;i<16*32;i+=512){
        int row = i>>5, f4 = i&31;
        *(float4*)&senc[row*132 + f4*4] = ((const float4*)(enc + (size_t)(b0+row)*128))[f4];
    }
    __syncthreads();

    v8s ah[4], al[4];
#pragma unroll
    for (int kb=0;kb<4;kb++) cvt8(&senc[ln*132 + kb*32 + q*8], ah[kb], al[kb]);

    const v8s* FH = (const v8s*)GIh;
    const v8s* FL = (const v8s*)GIl;
#pragma unroll
    for (int u=0;u<4;u++){
        int nt = w*4 + u;
        int col = nt*16 + ln;
        float bb = bih0[col] + bhh0[col];
        v4f acc = {bb,bb,bb,bb};
#pragma unroll
        for (int kb=0;kb<4;kb++){
            v8s bh = FH[(nt*4+kb)*64 + l];
            v8s bl = FL[(nt*4+kb)*64 + l];
            acc = MFMA16(ah[kb],bh,acc); acc = MFMA16(al[kb],bh,acc); acc = MFMA16(ah[kb],bl,acc);
        }
#pragma unroll
        for (int i=0;i<4;i++)
            gi0[(size_t)(b0 + q*4 + i)*512 + col] = acc[i];
    }
}

// ---------------- 2-layer LSTM decoder v8: 1 barrier/step + LDS XOR swizzle ----------------
// R15: same 8-way write-bank conflict as the encoder (bank = 16(q&1)+4i+jw>>1)
// -> apply the same bijective swizzle off ^= ((row>>1)&7)<<3 to h0/h1 LDS.
#define LMB 16
__global__ __launch_bounds__(512)
__attribute__((amdgpu_waves_per_eu(2,2)))
void lstm_mfma(
    const float* __restrict__ gi0,
    const unsigned short* __restrict__ B0h,
    const unsigned short* __restrict__ B1h,
    const float* __restrict__ bih1, const float* __restrict__ bhh1,
    const float* __restrict__ Wop, const float* __restrict__ bop,
    float* __restrict__ outp)
{
    __shared__ int4 sW0[32*4*64];                                // 131072 B
    __shared__ unsigned short h0hi[2][4*512], h0lo[2][4*512];    // 16384 B
    __shared__ unsigned short h1hi[2][4*512], h1lo[2][4*512];    // 16384 B
    const int tid = threadIdx.x;
    const int l = tid & 63;
    const int w = tid >> 6;
    const int c = l & 15;
    const int q = l >> 4;
    const int j = w*16 + c;
    const int b0 = blockIdx.x*LMB;
    const int lsw = ((l>>1)&7)<<3;     // read swizzle key (row = l)

    {
        const int4* F0 = (const int4*)B0h;
        for (int i=tid;i<32*4*64;i+=512) sW0[i] = F0[i];
    }
    for (int i=tid;i<4*512;i+=512){
        h0hi[0][i]=0; h0lo[0][i]=0; h0hi[1][i]=0; h0lo[1][i]=0;
        h1hi[0][i]=0; h1lo[0][i]=0; h1hi[1][i]=0; h1lo[1][i]=0;
    }

    int4 W1r[32];
    {
        const int4* F1 = (const int4*)B1h;
#pragma unroll
        for (int g=0;g<4;g++)
#pragma unroll
            for (int kb=0;kb<8;kb++) W1r[g*8+kb] = F1[((g*8+w)*8 + kb)*64 + l];
#pragma unroll
        for (int i=0;i<32;i++)
            asm volatile("" : "+v"(W1r[i].x), "+v"(W1r[i].y), "+v"(W1r[i].z), "+v"(W1r[i].w));
    }

    float rgi[4][4];
#pragma unroll
    for (int g=0;g<4;g++)
#pragma unroll
        for (int i=0;i<4;i++)
            rgi[g][i] = gi0[(size_t)(b0 + q*4 + i)*512 + g*128 + j];

    float b1[4];
#pragma unroll
    for (int g=0;g<4;g++) b1[g] = bih1[g*128+j] + bhh1[g*128+j];
    float c0[4] = {0,0,0,0}, c1[4] = {0,0,0,0};
    const float wop0 = Wop[j], wop1 = Wop[128 + j];
    const float bo0 = bop[0], bo1 = bop[1];
    const int kbw = j>>5, qw = (j>>3)&3, jw = j&7;
    __syncthreads();

    int p = 0;
#pragma unroll 1
    for (int t=0;t<OUTL;t++){
        // ---- layer 0: read h0[p], write h0[1-p]; dual hi/lo accumulators ----
        v4f aH[4], aL[4];
#pragma unroll
        for (int g=0;g<4;g++){
            v4f t4 = {rgi[g][0], rgi[g][1], rgi[g][2], rgi[g][3]};
            aH[g] = t4;
            v4f z = {0.f,0.f,0.f,0.f};
            aL[g] = z;
        }
#pragma unroll
        for (int kb=0;kb<4;kb++){
            v8s ah = *(const v8s*)&h0hi[p][kb*512 + ((l*8) ^ lsw)];
            v8s al = *(const v8s*)&h0lo[p][kb*512 + ((l*8) ^ lsw)];
#pragma unroll
            for (int g=0;g<4;g++){
                v8s bfr = as_v8s(sW0[((g*8+w)*4 + kb)*64 + l]);
                aH[g] = MFMA16(ah, bfr, aH[g]);
                aL[g] = MFMA16(al, bfr, aL[g]);
            }
        }
#pragma unroll
        for (int i=0;i<4;i++){
            float gi_ = aH[0][i]+aL[0][i], gf_ = aH[1][i]+aL[1][i];
            float gg_ = aH[2][i]+aL[2][i], go_ = aH[3][i]+aL[3][i];
            c0[i] = fsig(gf_)*c0[i] + fsig(gi_)*ftanh(gg_);
            float hn = fsig(go_)*ftanh(c0[i]);
            int row = q*4 + i;
            int off = (kbw*512 + (qw*16 + row)*8 + jw) ^ (((row>>1)&7)<<3);
            unsigned short h = f2bf(hn);
            h0hi[1-p][off] = h;
            h0lo[1-p][off] = f2bf(hn - bf2f(h));
        }
        __syncthreads();   // B1: the ONLY barrier per step

        // ---- layer 1: read h0[1-p] + h1[p], write h1[1-p] ----
        v4f bH[4], bL[4];
#pragma unroll
        for (int g=0;g<4;g++){
            v4f t4={b1[g],b1[g],b1[g],b1[g]}; bH[g]=t4;
            v4f z={0.f,0.f,0.f,0.f}; bL[g]=z;
        }
#pragma unroll
        for (int kb=0;kb<8;kb++){
            const unsigned short* hb = (kb<4) ? h0hi[1-p] : h1hi[p];
            const unsigned short* lb = (kb<4) ? h0lo[1-p] : h1lo[p];
            int kk = kb & 3;
            v8s ah = *(const v8s*)&hb[kk*512 + ((l*8) ^ lsw)];
            v8s al = *(const v8s*)&lb[kk*512 + ((l*8) ^ lsw)];
#pragma unroll
            for (int g=0;g<4;g++){
                bH[g] = MFMA16(ah, as_v8s(W1r[g*8+kb]), bH[g]);
                bL[g] = MFMA16(al, as_v8s(W1r[g*8+kb]), bL[g]);
            }
        }
        float h1new[4];
#pragma unroll
        for (int i=0;i<4;i++){
            float gi_ = bH[0][i]+bL[0][i], gf_ = bH[1][i]+bL[1][i];
            float gg_ = bH[2][i]+bL[2][i], go_ = bH[3][i]+bL[3][i];
            c1[i] = fsig(gf_)*c1[i] + fsig(gi_)*ftanh(gg_);
            h1new[i] = fsig(go_)*ftanh(c1[i]);
            int row = q*4 + i;
            int off = (kbw*512 + (qw*16 + row)*8 + jw) ^ (((row>>1)&7)<<3);
            unsigned short h = f2bf(h1new[i]);
            h1hi[1-p][off] = h;
            h1lo[1-p][off] = f2bf(h1new[i] - bf2f(h));
        }

        // ---- out-proj: register partials, wave shuffle-reduce, atomicAdd ----
        {
            float v0[4], v1[4];
#pragma unroll
            for (int i=0;i<4;i++){ v0[i] = h1new[i]*wop0; v1[i] = h1new[i]*wop1; }
#pragma unroll
            for (int m=1;m<16;m<<=1){
#pragma unroll
                for (int i=0;i<4;i++){
                    v0[i] += __shfl_xor(v0[i], m);
                    v1[i] += __shfl_xor(v1[i], m);
                }
            }
            if (c == 0){
                if (w == 0){
#pragma unroll
                    for (int i=0;i<4;i++){ v0[i] += bo0; v1[i] += bo1; }
                }
#pragma unroll
                for (int i=0;i<4;i++){
                    size_t base = (size_t)(b0 + q*4 + i)*(OUTL*2) + t*2;
                    atomicAdd(&outp[base    ], v0[i]);
                    atomicAdd(&outp[base + 1], v1[i]);
                }
            }
        }
        p ^= 1;
    }
}

extern "C" void kernel_launch(void* const* d_in, const int* in_sizes, int n_in,
                              void* d_out, int out_size, void* d_ws, size_t ws_size,
                              hipStream_t stream)
{
    const float* x    = (const float*)d_in[0];
    const int*   ei   = (const int*)d_in[1];
    const float* ea   = (const float*)d_in[2];
    const int*   tgt  = (const int*)d_in[3];
    const float* Wip  = (const float*)d_in[4];
    const float* bip  = (const float*)d_in[5];
    const float* gWih = (const float*)d_in[6];
    const float* gWhh = (const float*)d_in[7];
    const float* gbih = (const float*)d_in[8];
    const float* gbhh = (const float*)d_in[9];
    const float* Wdyn = (const float*)d_in[10];
    const float* bdyn = (const float*)d_in[11];
    const float* c1Wf=(const float*)d_in[12]; const float* c1bf=(const float*)d_in[13];
    const float* c1Ws=(const float*)d_in[14]; const float* c1bs=(const float*)d_in[15];
    const float* c1g =(const float*)d_in[16]; const float* c1b =(const float*)d_in[17];
    const float* c1m =(const float*)d_in[18]; const float* c1v =(const float*)d_in[19];
    const float* c2Wf=(const float*)d_in[20]; const float* c2bf=(const float*)d_in[21];
    const float* c2Ws=(const float*)d_in[22]; const float* c2bs=(const float*)d_in[23];
    const float* c2g =(const float*)d_in[24]; const float* c2b =(const float*)d_in[25];
    const float* c2m =(const float*)d_in[26]; const float* c2v =(const float*)d_in[27];
    const float* Wn  =(const float*)d_in[28]; const float* bn_ =(const float*)d_in[29];
    const float* l0Wih=(const float*)d_in[30]; const float* l0Whh=(const float*)d_in[31];
    const float* l0bih=(const float*)d_in[32]; const float* l0bhh=(const float*)d_in[33];
    const float* l1Wih=(const float*)d_in[34]; const float* l1Whh=(const float*)d_in[35];
    const float* l1bih=(const float*)d_in[36]; const float* l1bhh=(const float*)d_in[37];
    const float* Wop =(const float*)d_in[38]; const float* bop=(const float*)d_in[39];

    float* ws = (float*)d_ws;
    size_t o = 0;
    float* hist = ws + o; o += (size_t)NN*ENC;
    float* f1   = ws + o; o += (size_t)NN*ENC;
    float* f2   = ws + o; o += (size_t)NN*ENC;
    float* Af   = ws + o; o += (size_t)NN*ENC;
    float* Bf   = ws + o; o += (size_t)NN*ENC;
    float* As   = ws + o; o += (size_t)NN*ENC;
    float* Bs   = ws + o; o += (size_t)NN*ENC;
    float* enc  = ws + o; o += (size_t)BB*2*ENC;
    float* gi0  = ws + o; o += (size_t)BB*4*DEC;
    unsigned short* pWih  = (unsigned short*)(ws + o); o += (size_t)12*64*8/2;
    unsigned short* pWhh  = (unsigned short*)(ws + o); o += (size_t)24*64*8/2;
    unsigned short* pWdyn = (unsigned short*)(ws + o); o += (size_t)8*64*8/2;
    unsigned short* B0h = (unsigned short*)(ws + o); o += (size_t)32*4*64*8/2;
    unsigned short* B1h = (unsigned short*)(ws + o); o += (size_t)32*8*64*8/2;
    unsigned short* P1h = (unsigned short*)(ws + o); o += (size_t)2048*8/2;
    unsigned short* P1l = (unsigned short*)(ws + o); o += (size_t)2048*8/2;
    unsigned short* P2h = (unsigned short*)(ws + o); o += (size_t)2048*8/2;
    unsigned short* P2l = (unsigned short*)(ws + o); o += (size_t)2048*8/2;
    unsigned short* GIh = (unsigned short*)(ws + o); o += (size_t)8192*8/2;
    unsigned short* GIl = (unsigned short*)(ws + o); o += (size_t)8192*8/2;
    int* cnt    = (int*)(ws + o); o += NN;
    int* offv   = (int*)(ws + o); o += NN+1;
    int* curv   = (int*)(ws + o); o += NN;
    int* gtot   = (int*)(ws + o); o += 1;
    o = (o + 3) & ~(size_t)3;               // align to 16B for int4 records
    int4* recS  = (int4*)(ws + o); o += (size_t)4*EE;

    // --- all weight prep + cnt/gtot zero in one dispatch ---
    pack_all<<<(PACK_TOTAL+255)/256, 256, 0, stream>>>(
        gWih, gWhh, Wdyn, l0Whh, l1Wih, l1Whh, l0Wih,
        c1Wf, c1Ws, c2Wf, c2Ws,
        pWih, pWhh, pWdyn, B0h, B1h, P1h, P1l, P2h, P2l, GIh, GIl, cnt, gtot);

    // --- zero output (lstm accumulates via atomics) ---
    (void)hipMemsetAsync(d_out, 0, (size_t)out_size*sizeof(float), stream);

    // --- dst segment build (order-free atomic allocation) ---
    count_kernel<<<(EE+255)/256, 256, 0, stream>>>(ei, cnt);
    alloc_kernel<<<(NN+255)/256, 256, 0, stream>>>(cnt, gtot, offv, curv);
    scatter_kernel<<<(EE+255)/256, 256, 0, stream>>>(ei, ea, curv, recS);

    // --- history encoder (MFMA, 4 light waves, swizzled LDS) ---
    encoder_mfma<<<NN/16, 256, 0, stream>>>(x, Wip, bip, pWih, pWhh, gbih, gbhh, pWdyn, bdyn, hist);

    // --- CGConv 1 ---
    proj_mfma<<<(NN+63)/64, 256, 0, stream>>>(hist, P1h, P1l, Af,Bf,As,Bs);
    cg_agg<<<(NN+3)/4, 256, 0, stream>>>(hist, recS, offv, cnt,
                                         c1Wf,c1bf,c1Ws,c1bs, Af,Bf,As,Bs,
                                         c1g,c1b,c1m,c1v, f1);

    // --- CGConv 2 ---
    proj_mfma<<<(NN+63)/64, 256, 0, stream>>>(f1, P2h, P2l, Af,Bf,As,Bs);
    cg_agg<<<(NN+3)/4, 256, 0, stream>>>(f1, recS, offv, cnt,
                                         c2Wf,c2bf,c2Ws,c2bs, Af,Bf,As,Bs,
                                         c2g,c2b,c2m,c2v, f2);

    // --- target encoding ---
    target_kernel<<<(BB+3)/4, 256, 0, stream>>>(hist, f2, tgt, Wn, bn_, enc);

    // --- LSTM decoder prep (MFMA gi0) ---
    gi0_mfma<<<BB/16, 512, 0, stream>>>(enc, GIh, GIl, l0bih, l0bhh, gi0);

    // --- LSTM decoder (1-barrier t-loop) ---
    lstm_mfma<<<BB/LMB, 512, 0, stream>>>(gi0, B0h, B1h,
                                          l1bih, l1bhh, Wop, bop, (float*)d_out);
}

// Round 5
// 601.990 us; speedup vs baseline: 1.0446x; 1.0219x over previous
//
#include <hip/hip_runtime.h>
#include <math.h>

#define NN   50000
#define TT   16
#define EE   800000
#define BB   2000
#define EMBD 32
#define ENC  64
#define DEC  128
#define OUTL 25
#define BN_EPS 1e-5f

typedef short v8s __attribute__((ext_vector_type(8)));
typedef float v4f __attribute__((ext_vector_type(4)));
#define MFMA16(a,b,c) __builtin_amdgcn_mfma_f32_16x16x32_bf16((a),(b),(c),0,0,0)

__device__ __forceinline__ float lrelu(float v){ return v >= 0.f ? v : 0.1f*v; }
__device__ __forceinline__ float fsig(float v){ return __builtin_amdgcn_rcpf(1.f + __expf(-v)); }
__device__ __forceinline__ float ftanh(float v){ return 2.f*__builtin_amdgcn_rcpf(1.f + __expf(-2.f*v)) - 1.f; }
__device__ __forceinline__ float fsoftplus(float v){
    return v > 15.f ? v : __logf(1.f + __expf(v));
}
__device__ __forceinline__ float hsum(float4 a){ return (a.x+a.y)+(a.z+a.w); }

__device__ __forceinline__ unsigned short f2bf(float f){
    unsigned u = __float_as_uint(f);
    u = u + 0x7FFFu + ((u>>16)&1u);
    return (unsigned short)(u>>16);
}
__device__ __forceinline__ float bf2f(unsigned short s){ return __uint_as_float(((unsigned)s)<<16); }

// truncation-based hi/lo split (R12): hi = truncated bf16, lo = bf16 of the
// exact residual; ~4 VALU ops vs ~8 for the RNE pair, same net precision.
__device__ __forceinline__ void tsplit(float v, unsigned short& hi, unsigned short& lo){
    unsigned u = __float_as_uint(v);
    hi = (unsigned short)(u >> 16);
    float r = v - __uint_as_float(u & 0xFFFF0000u);
    lo = (unsigned short)(__float_as_uint(r) >> 16);
}

__device__ __forceinline__ v8s as_v8s(int4 v){
    union { int4 i; v8s s; } u; u.i = v; return u.s;
}

__device__ __forceinline__ void cvt8(const float* p, v8s& hi, v8s& lo){
    float4 a0 = *(const float4*)p;
    float4 a1 = *(const float4*)(p+4);
    float av[8] = {a0.x,a0.y,a0.z,a0.w,a1.x,a1.y,a1.z,a1.w};
#pragma unroll
    for (int j=0;j<8;j++){
        unsigned short h = f2bf(av[j]);
        hi[j] = (short)h;
        lo[j] = (short)f2bf(av[j] - bf2f(h));
    }
}
// reconstruct hi+lo, lrelu, re-split
__device__ __forceinline__ void lrelu_resplit(v8s hh, v8s hl, v8s& oh, v8s& ol){
#pragma unroll
    for (int j=0;j<8;j++){
        float v = bf2f((unsigned short)hh[j]) + bf2f((unsigned short)hl[j]);
        float a = lrelu(v);
        unsigned short h = f2bf(a);
        oh[j] = (short)h;
        ol[j] = (short)f2bf(a - bf2f(h));
    }
}

// ---------------- fused packing helpers ----------------
__device__ __forceinline__ void pf_item(const float* W, int K, int KB, int i,
                                        unsigned short* out){
    int l = i & 63, fb = i >> 6;
    int kb = fb % KB, nt = fb / KB;
    int n = nt*16 + (l&15);
    int k0 = kb*32 + ((l>>4)*8);
#pragma unroll
    for (int j=0;j<8;j++) out[i*8+j] = f2bf(W[(size_t)n*K + k0 + j]);
}
__device__ __forceinline__ void phl_item(const float* W, int K, int KB, int i,
                                         unsigned short* hi, unsigned short* lo){
    int l = i & 63, fb = i >> 6;
    int kb = fb % KB, nt = fb / KB;
    int n = nt*16 + (l&15);
    int k0 = kb*32 + ((l>>4)*8);
#pragma unroll
    for (int j=0;j<8;j++){
        float v = W[(size_t)n*K + k0 + j];
        unsigned short h = f2bf(v);
        hi[i*8+j] = h;
        lo[i*8+j] = f2bf(v - bf2f(h));
    }
}
__device__ __forceinline__ void pcat_item(const float* Wa, const float* Wb,
                                          int K1, int K, int KB, int i,
                                          unsigned short* out){
    int l = i & 63, fb = i >> 6;
    int kb = fb % KB, nt = fb / KB;
    int n = nt*16 + (l&15);
    int k0 = kb*32 + ((l>>4)*8);
#pragma unroll
    for (int j=0;j<8;j++){
        int k = k0 + j;
        float v = (k < K1) ? Wa[(size_t)n*K1 + k] : Wb[(size_t)n*(K-K1) + (k-K1)];
        out[i*8+j] = f2bf(v);
    }
}
__device__ __forceinline__ void pproj_item(const float* Wf, const float* Ws, int i,
                                           unsigned short* hi, unsigned short* lo){
    int l = i & 63, fb = i >> 6;
    int kb = fb & 1, nt = fb >> 1;
    int n = nt*16 + (l&15);
    int d = n >> 6, c = n & 63;
    const float* W = (d < 2) ? Wf : Ws;
    int k0 = (d&1)*64 + kb*32 + ((l>>4)*8);
#pragma unroll
    for (int j=0;j<8;j++){
        float v = W[c*130 + k0 + j];
        unsigned short h = f2bf(v);
        hi[i*8+j] = h;
        lo[i*8+j] = f2bf(v - bf2f(h));
    }
}

// ---------------- all weight prep in ONE dispatch ----------------
__global__ void pack_all(
    const float* __restrict__ gWih, const float* __restrict__ gWhh,
    const float* __restrict__ Wdyn,
    const float* __restrict__ l0Whh, const float* __restrict__ l1Wih,
    const float* __restrict__ l1Whh, const float* __restrict__ l0Wih,
    const float* __restrict__ c1Wf, const float* __restrict__ c1Ws,
    const float* __restrict__ c2Wf, const float* __restrict__ c2Ws,
    unsigned short* __restrict__ pWih, unsigned short* __restrict__ pWhh,
    unsigned short* __restrict__ pWdyn,
    unsigned short* __restrict__ B0h, unsigned short* __restrict__ B1h,
    unsigned short* __restrict__ P1h, unsigned short* __restrict__ P1l,
    unsigned short* __restrict__ P2h, unsigned short* __restrict__ P2l,
    unsigned short* __restrict__ GIh, unsigned short* __restrict__ GIl,
    int* __restrict__ cnt, int* __restrict__ gtot)
{
    int i = blockIdx.x*256 + threadIdx.x;
    if (i < 768){ pf_item(gWih, 32, 1, i, pWih); return; }   i -= 768;
    if (i < 1536){ pf_item(gWhh, 64, 2, i, pWhh); return; }  i -= 1536;
    if (i < 512){ pf_item(Wdyn, 64, 2, i, pWdyn); return; }  i -= 512;
    if (i < 8192){ pcat_item(l0Whh, l0Whh, 128, 128, 4, i, B0h); return; } i -= 8192;
    if (i < 16384){ pcat_item(l1Wih, l1Whh, 128, 256, 8, i, B1h); return; } i -= 16384;
    if (i < 2048){ pproj_item(c1Wf, c1Ws, i, P1h, P1l); return; } i -= 2048;
    if (i < 2048){ pproj_item(c2Wf, c2Ws, i, P2h, P2l); return; } i -= 2048;
    if (i < 8192){ phl_item(l0Wih, 128, 4, i, GIh, GIl); return; } i -= 8192;
    if (i < NN){ cnt[i] = 0; return; } i -= NN;
    if (i < 1){ gtot[0] = 0; return; }
}
#define PACK_TOTAL (768+1536+512+8192+16384+2048+2048+8192+NN+1)

// ---------------- GRU encoder v9: e-frags precomputed, lean t-loop ----------------
// R16 post-mortem of v8: occupancy doubled (28%), VGPR 72, but dur flat at
// 109us and VALUBusy 70% -> VALU-instruction-throughput-bound. The ~470
// instrs/step decompose as ~96 e-frag compute (DUPLICATED in all 4 waves,
// recomputed all 16 steps) + ~100 gates + addressing. Bank conflicts did NOT
// move with the swizzle (write-traffic-proportional, off critical path).
// v9: e_t is h-independent -> precompute ALL 16 steps' e-frags in a prologue
// (wave w does steps 4w..4w+3; b128 stores; no duplication, 16x less e-work),
// hot loop reads them back with 2 ds_read_b128. Bit-identical numerics.
// LDS 43KB (cap 3 blk/CU = 37% occ, above achieved 28%).
__global__ __launch_bounds__(256) void encoder_mfma(
    const float* __restrict__ x,
    const float* __restrict__ Wip, const float* __restrict__ bip,
    const unsigned short* __restrict__ pWih,
    const unsigned short* __restrict__ pWhh,
    const float* __restrict__ bih, const float* __restrict__ bhh,
    const unsigned short* __restrict__ pWdyn,
    const float* __restrict__ bdyn,
    float* __restrict__ hist)
{
    __shared__ float sxt[512];                                 // x transposed [t][m][c]
    __shared__ unsigned short efh[16*512], efl[16*512];        // e A-frags, all 16 steps
    __shared__ unsigned short hfh[2][1024], hfl[2][1024];      // dbuf h A-frags (swizzled)
    const int tid = threadIdx.x;
    const int l   = tid & 63;
    const int w   = tid >> 6;          // wave owns g-tile w
    const int ln  = l & 15, q = l >> 4;
    const int blk = blockIdx.x;
    const int rsw = ((l>>1)&7)<<3;     // read swizzle key

    for (int idx = tid; idx < 512; idx += 256){
        int m = idx >> 5, r = idx & 31;                        // r = t*2 + c
        sxt[(r>>1)*32 + m*2 + (r&1)] = x[(size_t)blk*512 + idx];
    }
    for (int i = tid; i < 1024; i += 256){
        hfh[0][i]=0; hfl[0][i]=0; hfh[1][i]=0; hfl[1][i]=0;
    }

    // per-lane input-projection weights for k = q*8+j (live only in prologue)
    float w0[8], w1[8], bk[8];
#pragma unroll
    for (int j = 0; j < 8; j++){
        int k = q*8 + j;
        w0[j] = Wip[2*k]; w1[j] = Wip[2*k+1]; bk[j] = bip[k];
    }
    __syncthreads();                   // sxt ready

    // ---- prologue: wave w computes e-frags for t = 4w..4w+3 ----
#pragma unroll
    for (int tt = 0; tt < 4; tt++){
        int t = w*4 + tt;
        float2 xv = *(const float2*)&sxt[t*32 + ln*2];
        v8s eh, el;
#pragma unroll
        for (int j = 0; j < 8; j++){
            float e = lrelu(w0[j]*xv.x + w1[j]*xv.y + bk[j]);
            unsigned short h_, l_;
            tsplit(e, h_, l_);
            eh[j] = (short)h_; el[j] = (short)l_;
        }
        *(v8s*)&efh[t*512 + l*8] = eh;      // b128, conflict-free
        *(v8s*)&efl[t*512 + l*8] = el;
    }

    const int c = w*16 + ln;
    const float bR  = bih[c]       + bhh[c];
    const float bZ  = bih[64 + c]  + bhh[64 + c];
    const float bNI = bih[128 + c];
    const float bNH = bhh[128 + c];
    float hprev[4] = {0.f,0.f,0.f,0.f};

    const v8s* FIH = (const v8s*)pWih;
    const v8s* FHH = (const v8s*)pWhh;
    const v8s* FDY = (const v8s*)pWdyn;
    const int wbase = (c>>5)*512 + (16*((c&31)>>3))*8 + (c&7);
    __syncthreads();                   // e-frags + h zero-init ready

    int p = 0;
#pragma unroll 1
    for (int t = 0; t < TT; t++){
        v8s eh  = *(const v8s*)&efh[t*512 + l*8];
        v8s el  = *(const v8s*)&efl[t*512 + l*8];
        v8s h0h = *(const v8s*)&hfh[p][(l*8) ^ rsw];
        v8s h0l = *(const v8s*)&hfl[p][(l*8) ^ rsw];
        v8s h1h = *(const v8s*)&hfh[p][512 + ((l*8) ^ rsw)];
        v8s h1l = *(const v8s*)&hfl[p][512 + ((l*8) ^ rsw)];

        v4f aR = {bR,bR,bR,bR};
        v4f aZ = {bZ,bZ,bZ,bZ};
        v4f aNI= {bNI,bNI,bNI,bNI};
        v4f aNH= {bNH,bNH,bNH,bNH};
        v8s b;
        b = FIH[(w   )*64 + l];    aR = MFMA16(eh,b,aR);  aR = MFMA16(el,b,aR);
        b = FHH[(w*2+0)*64+l];     aR = MFMA16(h0h,b,aR); aR = MFMA16(h0l,b,aR);
        b = FHH[(w*2+1)*64+l];     aR = MFMA16(h1h,b,aR); aR = MFMA16(h1l,b,aR);
        b = FIH[(4+w )*64 + l];    aZ = MFMA16(eh,b,aZ);  aZ = MFMA16(el,b,aZ);
        b = FHH[((4+w)*2+0)*64+l]; aZ = MFMA16(h0h,b,aZ); aZ = MFMA16(h0l,b,aZ);
        b = FHH[((4+w)*2+1)*64+l]; aZ = MFMA16(h1h,b,aZ); aZ = MFMA16(h1l,b,aZ);
        b = FIH[(8+w )*64 + l];    aNI= MFMA16(eh,b,aNI); aNI= MFMA16(el,b,aNI);
        b = FHH[((8+w)*2+0)*64+l]; aNH= MFMA16(h0h,b,aNH);aNH= MFMA16(h0l,b,aNH);
        b = FHH[((8+w)*2+1)*64+l]; aNH= MFMA16(h1h,b,aNH);aNH= MFMA16(h1l,b,aNH);

#pragma unroll
        for (int i = 0; i < 4; i++){
            float r_ = fsig(aR[i]);
            float z_ = fsig(aZ[i]);
            float nn_ = ftanh(aNI[i] + r_*aNH[i]);
            float hn = nn_ + z_*(hprev[i] - nn_);
            hprev[i] = hn;
            int row = q*4 + i;
            int off = (wbase + row*8) ^ ((((row)>>1)&7)<<3);
            unsigned short hh_, hl_;
            tsplit(hn, hh_, hl_);
            hfh[1-p][off] = hh_;
            hfl[1-p][off] = hl_;
        }
        __syncthreads();   // the ONLY barrier per step
        p ^= 1;
    }
    {
        v8s a0h,a0l,a1h,a1l;
        lrelu_resplit(*(const v8s*)&hfh[p][(l*8) ^ rsw],
                      *(const v8s*)&hfl[p][(l*8) ^ rsw],       a0h, a0l);
        lrelu_resplit(*(const v8s*)&hfh[p][512 + ((l*8) ^ rsw)],
                      *(const v8s*)&hfl[p][512 + ((l*8) ^ rsw)], a1h, a1l);
        const int nt = w;
        float bb = bdyn[nt*16 + ln];
        v4f acc = {bb,bb,bb,bb};
        v8s b;
        b = FDY[(nt*2+0)*64 + l]; acc = MFMA16(a0h,b,acc); acc = MFMA16(a0l,b,acc);
        b = FDY[(nt*2+1)*64 + l]; acc = MFMA16(a1h,b,acc); acc = MFMA16(a1l,b,acc);
#pragma unroll
        for (int i = 0; i < 4; i++){
            hist[(size_t)(blk*16 + q*4 + i)*64 + nt*16 + ln] = lrelu(acc[i]);
        }
    }
}

// ---------------- CGConv projections: MFMA (unchanged) ----------------
__global__ __launch_bounds__(256) void proj_mfma(
    const float* __restrict__ xin,
    const unsigned short* __restrict__ Bh, const unsigned short* __restrict__ Bl,
    float* __restrict__ Af, float* __restrict__ Bf,
    float* __restrict__ As, float* __restrict__ Bs)
{
    __shared__ float sx[64*68];
    const int tid = threadIdx.x;
    const int l = tid & 63;
    const int w = tid >> 6;
    const int ln = l & 15, q = l >> 4;
    const int n0 = blockIdx.x*64;

    for (int i=tid;i<64*16;i+=256){
        int nn = i>>4, f4 = i&15;
        float4 v = {0.f,0.f,0.f,0.f};
        if (n0+nn < NN) v = ((const float4*)(xin + (size_t)(n0+nn)*64))[f4];
        *(float4*)&sx[nn*68 + f4*4] = v;
    }
    __syncthreads();

    v8s ah0,al0,ah1,al1;
    cvt8(&sx[(w*16+ln)*68 +      q*8], ah0, al0);
    cvt8(&sx[(w*16+ln)*68 + 32 + q*8], ah1, al1);

    const v8s* FH = (const v8s*)Bh;
    const v8s* FL = (const v8s*)Bl;
#pragma unroll 1
    for (int nt=0; nt<16; nt++){
        v8s bh0 = FH[(nt*2+0)*64 + l], bl0 = FL[(nt*2+0)*64 + l];
        v8s bh1 = FH[(nt*2+1)*64 + l], bl1 = FL[(nt*2+1)*64 + l];
        v4f acc = {0.f,0.f,0.f,0.f};
        acc = MFMA16(ah0,bh0,acc); acc = MFMA16(al0,bh0,acc); acc = MFMA16(ah0,bl0,acc);
        acc = MFMA16(ah1,bh1,acc); acc = MFMA16(al1,bh1,acc); acc = MFMA16(ah1,bl1,acc);
        int d = nt >> 2, col = (nt&3)*16 + ln;
        float* op = (d==0) ? Af : (d==1) ? Bf : (d==2) ? As : Bs;
#pragma unroll
        for (int i=0;i<4;i++){
            int node = n0 + w*16 + q*4 + i;
            if (node < NN) op[(size_t)node*64 + col] = acc[i];
        }
    }
}

// ---------------- dst segment build: histogram + atomic alloc + scatter ----------------
__global__ void count_kernel(const int* __restrict__ ei, int* __restrict__ cnt){
    int e = blockIdx.x*256 + threadIdx.x;
    if (e < EE) atomicAdd(&cnt[ei[EE+e]], 1);
}

__global__ void alloc_kernel(const int* __restrict__ cnt, int* __restrict__ gtot,
                             int* __restrict__ off, int* __restrict__ cur){
    int n = blockIdx.x*256 + threadIdx.x;
    if (n >= NN) return;
    int c = cnt[n];
    int s = atomicAdd(gtot, c);
    off[n] = s;
    cur[n] = s;
}

// scatter + pre-gather (src, e0, e1) into ONE int4 record per edge
__global__ void scatter_kernel(const int* __restrict__ ei, const float* __restrict__ ea,
                               int* __restrict__ cur, int4* __restrict__ recS){
    int e = blockIdx.x*256 + threadIdx.x;
    if (e >= EE) return;
    int d = ei[EE+e];
    int p = atomicAdd(&cur[d], 1);
    int4 r;
    r.x = ei[e];
    r.y = __float_as_int(ea[2*(size_t)e]);
    r.z = __float_as_int(ea[2*(size_t)e+1]);
    r.w = 0;
    recS[p] = r;
}

// ---------------- CGConv aggregate (packed records) ----------------
__global__ __launch_bounds__(256) void cg_agg(
    const float* __restrict__ xin,
    const int4* __restrict__ recS,
    const int* __restrict__ off, const int* __restrict__ cnt,
    const float* __restrict__ Wf, const float* __restrict__ bf,
    const float* __restrict__ Ws, const float* __restrict__ bs,
    const float* __restrict__ Af, const float* __restrict__ Bf,
    const float* __restrict__ As, const float* __restrict__ Bs,
    const float* __restrict__ gamma, const float* __restrict__ beta,
    const float* __restrict__ mean, const float* __restrict__ var,
    float* __restrict__ outp)
{
    const int tid = threadIdx.x;
    const int c = tid & 63, wid = tid >> 6;
    const int n = blockIdx.x*4 + wid;
    if (n >= NN) return;

    const float wf0 = Wf[c*130+128], wf1 = Wf[c*130+129], bfc = bf[c];
    const float ws0 = Ws[c*130+128], ws1 = Ws[c*130+129], bsc = bs[c];
    const float afd = Af[(size_t)n*64+c] + bfc, asd = As[(size_t)n*64+c] + bsc;
    const float* Bfc = Bf + c;
    const float* Bsc = Bs + c;

    float acc = 0.f;
    int i = off[n];
    const int i1 = i + cnt[n];
#pragma unroll 1
    for (; i+1 < i1; i += 2){
        int4 r0 = recS[i], r1 = recS[i+1];
        float e00 = __int_as_float(r0.y), e01 = __int_as_float(r0.z);
        float e10 = __int_as_float(r1.y), e11 = __int_as_float(r1.z);
        float bf0v = Bfc[(size_t)r0.x*64], bs0v = Bsc[(size_t)r0.x*64];
        float bf1v = Bfc[(size_t)r1.x*64], bs1v = Bsc[(size_t)r1.x*64];
        float gf0 = afd + bf0v + wf0*e00 + wf1*e01;
        float gs0 = asd + bs0v + ws0*e00 + ws1*e01;
        float gf1 = afd + bf1v + wf0*e10 + wf1*e11;
        float gs1 = asd + bs1v + ws0*e10 + ws1*e11;
        acc += fsig(gf0)*fsoftplus(gs0);
        acc += fsig(gf1)*fsoftplus(gs1);
    }
    if (i < i1){
        int4 r0 = recS[i];
        float e00 = __int_as_float(r0.y), e01 = __int_as_float(r0.z);
        float gf = afd + Bfc[(size_t)r0.x*64] + wf0*e00 + wf1*e01;
        float gs = asd + Bsc[(size_t)r0.x*64] + ws0*e00 + ws1*e01;
        acc += fsig(gf)*fsoftplus(gs);
    }
    float bn = (acc - mean[c])*rsqrtf(var[c]+BN_EPS)*gamma[c] + beta[c];
    outp[(size_t)n*64+c] = xin[(size_t)n*64+c] + bn;
}

// ---------------- target gather + nbrs linear + concat (unchanged) ----------------
__global__ __launch_bounds__(256) void target_kernel(
    const float* __restrict__ hist, const float* __restrict__ f2,
    const int* __restrict__ tgt,
    const float* __restrict__ Wn, const float* __restrict__ bn_,
    float* __restrict__ enc)
{
    const int tid=threadIdx.x;
    const int c = tid&63, q = tid>>6;
    const int b = blockIdx.x*4 + q;
    if (b>=BB) return;
    const int n = tgt[b];
    float a = bn_[c];
#pragma unroll
    for (int k=0;k<ENC;k++) a += Wn[c*64+k]*f2[(size_t)n*64+k];
    enc[(size_t)b*128 + 64 + c] = lrelu(a);
    enc[(size_t)b*128 + c]      = hist[(size_t)n*64+c];
}

// ---------------- gi0 via MFMA (unchanged) ----------------
__global__ __launch_bounds__(512) void gi0_mfma(
    const float* __restrict__ enc,
    const unsigned short* __restrict__ GIh, const unsigned short* __restrict__ GIl,
    const float* __restrict__ bih0, const float* __restrict__ bhh0,
    float* __restrict__ gi0)
{
    __shared__ float senc[16*132];
    const int tid = threadIdx.x;
    const int l = tid & 63;
    const int w = tid >> 6;
    const int ln = l & 15, q = l >> 4;
    const int b0 = blockIdx.x*16;

    for (int i=tid;i<16*32;i+=512){
        int row = i>>5, f4 = i&31;
        *(float4*)&senc[row*132 + f4*4] = ((const float4*)(enc + (size_t)(b0+row)*128))[f4];
    }
    __syncthreads();

    v8s ah[4], al[4];
#pragma unroll
    for (int kb=0;kb<4;kb++) cvt8(&senc[ln*132 + kb*32 + q*8], ah[kb], al[kb]);

    const v8s* FH = (const v8s*)GIh;
    const v8s* FL = (const v8s*)GIl;
#pragma unroll
    for (int u=0;u<4;u++){
        int nt = w*4 + u;
        int col = nt*16 + ln;
        float bb = bih0[col] + bhh0[col];
        v4f acc = {bb,bb,bb,bb};
#pragma unroll
        for (int kb=0;kb<4;kb++){
            v8s bh = FH[(nt*4+kb)*64 + l];
            v8s bl = FL[(nt*4+kb)*64 + l];
            acc = MFMA16(ah[kb],bh,acc); acc = MFMA16(al[kb],bh,acc); acc = MFMA16(ah[kb],bl,acc);
        }
#pragma unroll
        for (int i=0;i<4;i++)
            gi0[(size_t)(b0 + q*4 + i)*512 + col] = acc[i];
    }
}

// ---------------- 2-layer LSTM decoder v8: 1 barrier/step + LDS XOR swizzle ----------------
#define LMB 16
__global__ __launch_bounds__(512)
__attribute__((amdgpu_waves_per_eu(2,2)))
void lstm_mfma(
    const float* __restrict__ gi0,
    const unsigned short* __restrict__ B0h,
    const unsigned short* __restrict__ B1h,
    const float* __restrict__ bih1, const float* __restrict__ bhh1,
    const float* __restrict__ Wop, const float* __restrict__ bop,
    float* __restrict__ outp)
{
    __shared__ int4 sW0[32*4*64];                                // 131072 B
    __shared__ unsigned short h0hi[2][4*512], h0lo[2][4*512];    // 16384 B
    __shared__ unsigned short h1hi[2][4*512], h1lo[2][4*512];    // 16384 B
    const int tid = threadIdx.x;
    const int l = tid & 63;
    const int w = tid >> 6;
    const int c = l & 15;
    const int q = l >> 4;
    const int j = w*16 + c;
    const int b0 = blockIdx.x*LMB;
    const int lsw = ((l>>1)&7)<<3;     // read swizzle key (row = l)

    {
        const int4* F0 = (const int4*)B0h;
        for (int i=tid;i<32*4*64;i+=512) sW0[i] = F0[i];
    }
    for (int i=tid;i<4*512;i+=512){
        h0hi[0][i]=0; h0lo[0][i]=0; h0hi[1][i]=0; h0lo[1][i]=0;
        h1hi[0][i]=0; h1lo[0][i]=0; h1hi[1][i]=0; h1lo[1][i]=0;
    }

    int4 W1r[32];
    {
        const int4* F1 = (const int4*)B1h;
#pragma unroll
        for (int g=0;g<4;g++)
#pragma unroll
            for (int kb=0;kb<8;kb++) W1r[g*8+kb] = F1[((g*8+w)*8 + kb)*64 + l];
#pragma unroll
        for (int i=0;i<32;i++)
            asm volatile("" : "+v"(W1r[i].x), "+v"(W1r[i].y), "+v"(W1r[i].z), "+v"(W1r[i].w));
    }

    float rgi[4][4];
#pragma unroll
    for (int g=0;g<4;g++)
#pragma unroll
        for (int i=0;i<4;i++)
            rgi[g][i] = gi0[(size_t)(b0 + q*4 + i)*512 + g*128 + j];

    float b1[4];
#pragma unroll
    for (int g=0;g<4;g++) b1[g] = bih1[g*128+j] + bhh1[g*128+j];
    float c0[4] = {0,0,0,0}, c1[4] = {0,0,0,0};
    const float wop0 = Wop[j], wop1 = Wop[128 + j];
    const float bo0 = bop[0], bo1 = bop[1];
    const int kbw = j>>5, qw = (j>>3)&3, jw = j&7;
    __syncthreads();

    int p = 0;
#pragma unroll 1
    for (int t=0;t<OUTL;t++){
        // ---- layer 0: read h0[p], write h0[1-p]; dual hi/lo accumulators ----
        v4f aH[4], aL[4];
#pragma unroll
        for (int g=0;g<4;g++){
            v4f t4 = {rgi[g][0], rgi[g][1], rgi[g][2], rgi[g][3]};
            aH[g] = t4;
            v4f z = {0.f,0.f,0.f,0.f};
            aL[g] = z;
        }
#pragma unroll
        for (int kb=0;kb<4;kb++){
            v8s ah = *(const v8s*)&h0hi[p][kb*512 + ((l*8) ^ lsw)];
            v8s al = *(const v8s*)&h0lo[p][kb*512 + ((l*8) ^ lsw)];
#pragma unroll
            for (int g=0;g<4;g++){
                v8s bfr = as_v8s(sW0[((g*8+w)*4 + kb)*64 + l]);
                aH[g] = MFMA16(ah, bfr, aH[g]);
                aL[g] = MFMA16(al, bfr, aL[g]);
            }
        }
#pragma unroll
        for (int i=0;i<4;i++){
            float gi_ = aH[0][i]+aL[0][i], gf_ = aH[1][i]+aL[1][i];
            float gg_ = aH[2][i]+aL[2][i], go_ = aH[3][i]+aL[3][i];
            c0[i] = fsig(gf_)*c0[i] + fsig(gi_)*ftanh(gg_);
            float hn = fsig(go_)*ftanh(c0[i]);
            int row = q*4 + i;
            int off = (kbw*512 + (qw*16 + row)*8 + jw) ^ (((row>>1)&7)<<3);
            unsigned short h = f2bf(hn);
            h0hi[1-p][off] = h;
            h0lo[1-p][off] = f2bf(hn - bf2f(h));
        }
        __syncthreads();   // B1: the ONLY barrier per step

        // ---- layer 1: read h0[1-p] + h1[p], write h1[1-p] ----
        v4f bH[4], bL[4];
#pragma unroll
        for (int g=0;g<4;g++){
            v4f t4={b1[g],b1[g],b1[g],b1[g]}; bH[g]=t4;
            v4f z={0.f,0.f,0.f,0.f}; bL[g]=z;
        }
#pragma unroll
        for (int kb=0;kb<8;kb++){
            const unsigned short* hb = (kb<4) ? h0hi[1-p] : h1hi[p];
            const unsigned short* lb = (kb<4) ? h0lo[1-p] : h1lo[p];
            int kk = kb & 3;
            v8s ah = *(const v8s*)&hb[kk*512 + ((l*8) ^ lsw)];
            v8s al = *(const v8s*)&lb[kk*512 + ((l*8) ^ lsw)];
#pragma unroll
            for (int g=0;g<4;g++){
                bH[g] = MFMA16(ah, as_v8s(W1r[g*8+kb]), bH[g]);
                bL[g] = MFMA16(al, as_v8s(W1r[g*8+kb]), bL[g]);
            }
        }
        float h1new[4];
#pragma unroll
        for (int i=0;i<4;i++){
            float gi_ = bH[0][i]+bL[0][i], gf_ = bH[1][i]+bL[1][i];
            float gg_ = bH[2][i]+bL[2][i], go_ = bH[3][i]+bL[3][i];
            c1[i] = fsig(gf_)*c1[i] + fsig(gi_)*ftanh(gg_);
            h1new[i] = fsig(go_)*ftanh(c1[i]);
            int row = q*4 + i;
            int off = (kbw*512 + (qw*16 + row)*8 + jw) ^ (((row>>1)&7)<<3);
            unsigned short h = f2bf(h1new[i]);
            h1hi[1-p][off] = h;
            h1lo[1-p][off] = f2bf(h1new[i] - bf2f(h));
        }

        // ---- out-proj: register partials, wave shuffle-reduce, atomicAdd ----
        {
            float v0[4], v1[4];
#pragma unroll
            for (int i=0;i<4;i++){ v0[i] = h1new[i]*wop0; v1[i] = h1new[i]*wop1; }
#pragma unroll
            for (int m=1;m<16;m<<=1){
#pragma unroll
                for (int i=0;i<4;i++){
                    v0[i] += __shfl_xor(v0[i], m);
                    v1[i] += __shfl_xor(v1[i], m);
                }
            }
            if (c == 0){
                if (w == 0){
#pragma unroll
                    for (int i=0;i<4;i++){ v0[i] += bo0; v1[i] += bo1; }
                }
#pragma unroll
                for (int i=0;i<4;i++){
                    size_t base = (size_t)(b0 + q*4 + i)*(OUTL*2) + t*2;
                    atomicAdd(&outp[base    ], v0[i]);
                    atomicAdd(&outp[base + 1], v1[i]);
                }
            }
        }
        p ^= 1;
    }
}

extern "C" void kernel_launch(void* const* d_in, const int* in_sizes, int n_in,
                              void* d_out, int out_size, void* d_ws, size_t ws_size,
                              hipStream_t stream)
{
    const float* x    = (const float*)d_in[0];
    const int*   ei   = (const int*)d_in[1];
    const float* ea   = (const float*)d_in[2];
    const int*   tgt  = (const int*)d_in[3];
    const float* Wip  = (const float*)d_in[4];
    const float* bip  = (const float*)d_in[5];
    const float* gWih = (const float*)d_in[6];
    const float* gWhh = (const float*)d_in[7];
    const float* gbih = (const float*)d_in[8];
    const float* gbhh = (const float*)d_in[9];
    const float* Wdyn = (const float*)d_in[10];
    const float* bdyn = (const float*)d_in[11];
    const float* c1Wf=(const float*)d_in[12]; const float* c1bf=(const float*)d_in[13];
    const float* c1Ws=(const float*)d_in[14]; const float* c1bs=(const float*)d_in[15];
    const float* c1g =(const float*)d_in[16]; const float* c1b =(const float*)d_in[17];
    const float* c1m =(const float*)d_in[18]; const float* c1v =(const float*)d_in[19];
    const float* c2Wf=(const float*)d_in[20]; const float* c2bf=(const float*)d_in[21];
    const float* c2Ws=(const float*)d_in[22]; const float* c2bs=(const float*)d_in[23];
    const float* c2g =(const float*)d_in[24]; const float* c2b =(const float*)d_in[25];
    const float* c2m =(const float*)d_in[26]; const float* c2v =(const float*)d_in[27];
    const float* Wn  =(const float*)d_in[28]; const float* bn_ =(const float*)d_in[29];
    const float* l0Wih=(const float*)d_in[30]; const float* l0Whh=(const float*)d_in[31];
    const float* l0bih=(const float*)d_in[32]; const float* l0bhh=(const float*)d_in[33];
    const float* l1Wih=(const float*)d_in[34]; const float* l1Whh=(const float*)d_in[35];
    const float* l1bih=(const float*)d_in[36]; const float* l1bhh=(const float*)d_in[37];
    const float* Wop =(const float*)d_in[38]; const float* bop=(const float*)d_in[39];

    float* ws = (float*)d_ws;
    size_t o = 0;
    float* hist = ws + o; o += (size_t)NN*ENC;
    float* f1   = ws + o; o += (size_t)NN*ENC;
    float* f2   = ws + o; o += (size_t)NN*ENC;
    float* Af   = ws + o; o += (size_t)NN*ENC;
    float* Bf   = ws + o; o += (size_t)NN*ENC;
    float* As   = ws + o; o += (size_t)NN*ENC;
    float* Bs   = ws + o; o += (size_t)NN*ENC;
    float* enc  = ws + o; o += (size_t)BB*2*ENC;
    float* gi0  = ws + o; o += (size_t)BB*4*DEC;
    unsigned short* pWih  = (unsigned short*)(ws + o); o += (size_t)12*64*8/2;
    unsigned short* pWhh  = (unsigned short*)(ws + o); o += (size_t)24*64*8/2;
    unsigned short* pWdyn = (unsigned short*)(ws + o); o += (size_t)8*64*8/2;
    unsigned short* B0h = (unsigned short*)(ws + o); o += (size_t)32*4*64*8/2;
    unsigned short* B1h = (unsigned short*)(ws + o); o += (size_t)32*8*64*8/2;
    unsigned short* P1h = (unsigned short*)(ws + o); o += (size_t)2048*8/2;
    unsigned short* P1l = (unsigned short*)(ws + o); o += (size_t)2048*8/2;
    unsigned short* P2h = (unsigned short*)(ws + o); o += (size_t)2048*8/2;
    unsigned short* P2l = (unsigned short*)(ws + o); o += (size_t)2048*8/2;
    unsigned short* GIh = (unsigned short*)(ws + o); o += (size_t)8192*8/2;
    unsigned short* GIl = (unsigned short*)(ws + o); o += (size_t)8192*8/2;
    int* cnt    = (int*)(ws + o); o += NN;
    int* offv   = (int*)(ws + o); o += NN+1;
    int* curv   = (int*)(ws + o); o += NN;
    int* gtot   = (int*)(ws + o); o += 1;
    o = (o + 3) & ~(size_t)3;               // align to 16B for int4 records
    int4* recS  = (int4*)(ws + o); o += (size_t)4*EE;

    // --- all weight prep + cnt/gtot zero in one dispatch ---
    pack_all<<<(PACK_TOTAL+255)/256, 256, 0, stream>>>(
        gWih, gWhh, Wdyn, l0Whh, l1Wih, l1Whh, l0Wih,
        c1Wf, c1Ws, c2Wf, c2Ws,
        pWih, pWhh, pWdyn, B0h, B1h, P1h, P1l, P2h, P2l, GIh, GIl, cnt, gtot);

    // --- zero output (lstm accumulates via atomics) ---
    (void)hipMemsetAsync(d_out, 0, (size_t)out_size*sizeof(float), stream);

    // --- dst segment build (order-free atomic allocation) ---
    count_kernel<<<(EE+255)/256, 256, 0, stream>>>(ei, cnt);
    alloc_kernel<<<(NN+255)/256, 256, 0, stream>>>(cnt, gtot, offv, curv);
    scatter_kernel<<<(EE+255)/256, 256, 0, stream>>>(ei, ea, curv, recS);

    // --- history encoder (MFMA, e-frag precompute prologue) ---
    encoder_mfma<<<NN/16, 256, 0, stream>>>(x, Wip, bip, pWih, pWhh, gbih, gbhh, pWdyn, bdyn, hist);

    // --- CGConv 1 ---
    proj_mfma<<<(NN+63)/64, 256, 0, stream>>>(hist, P1h, P1l, Af,Bf,As,Bs);
    cg_agg<<<(NN+3)/4, 256, 0, stream>>>(hist, recS, offv, cnt,
                                         c1Wf,c1bf,c1Ws,c1bs, Af,Bf,As,Bs,
                                         c1g,c1b,c1m,c1v, f1);

    // --- CGConv 2 ---
    proj_mfma<<<(NN+63)/64, 256, 0, stream>>>(f1, P2h, P2l, Af,Bf,As,Bs);
    cg_agg<<<(NN+3)/4, 256, 0, stream>>>(f1, recS, offv, cnt,
                                         c2Wf,c2bf,c2Ws,c2bs, Af,Bf,As,Bs,
                                         c2g,c2b,c2m,c2v, f2);

    // --- target encoding ---
    target_kernel<<<(BB+3)/4, 256, 0, stream>>>(hist, f2, tgt, Wn, bn_, enc);

    // --- LSTM decoder prep (MFMA gi0) ---
    gi0_mfma<<<BB/16, 512, 0, stream>>>(enc, GIh, GIl, l0bih, l0bhh, gi0);

    // --- LSTM decoder (1-barrier t-loop) ---
    lstm_mfma<<<BB/LMB, 512, 0, stream>>>(gi0, B0h, B1h,
                                          l1bih, l1bhh, Wop, bop, (float*)d_out);
}

// Round 6
// 599.711 us; speedup vs baseline: 1.0485x; 1.0038x over previous
//
#include <hip/hip_runtime.h>
#include <math.h>

#define NN   50000
#define TT   16
#define EE   800000
#define BB   2000
#define EMBD 32
#define ENC  64
#define DEC  128
#define OUTL 25
#define BN_EPS 1e-5f

typedef short v8s __attribute__((ext_vector_type(8)));
typedef float v4f __attribute__((ext_vector_type(4)));
#define MFMA16(a,b,c) __builtin_amdgcn_mfma_f32_16x16x32_bf16((a),(b),(c),0,0,0)

__device__ __forceinline__ float lrelu(float v){ return v >= 0.f ? v : 0.1f*v; }
__device__ __forceinline__ float fsig(float v){ return __builtin_amdgcn_rcpf(1.f + __expf(-v)); }
__device__ __forceinline__ float ftanh(float v){ return 2.f*__builtin_amdgcn_rcpf(1.f + __expf(-2.f*v)) - 1.f; }
__device__ __forceinline__ float fsoftplus(float v){
    return v > 15.f ? v : __logf(1.f + __expf(v));
}
__device__ __forceinline__ float hsum(float4 a){ return (a.x+a.y)+(a.z+a.w); }

__device__ __forceinline__ unsigned short f2bf(float f){
    unsigned u = __float_as_uint(f);
    u = u + 0x7FFFu + ((u>>16)&1u);
    return (unsigned short)(u>>16);
}
__device__ __forceinline__ float bf2f(unsigned short s){ return __uint_as_float(((unsigned)s)<<16); }

// truncation-based hi/lo split (R12): hi = truncated bf16, lo = bf16 of the
// exact residual; ~4 VALU ops vs ~8 for the RNE pair, same net precision.
__device__ __forceinline__ void tsplit(float v, unsigned short& hi, unsigned short& lo){
    unsigned u = __float_as_uint(v);
    hi = (unsigned short)(u >> 16);
    float r = v - __uint_as_float(u & 0xFFFF0000u);
    lo = (unsigned short)(__float_as_uint(r) >> 16);
}

__device__ __forceinline__ v8s as_v8s(int4 v){
    union { int4 i; v8s s; } u; u.i = v; return u.s;
}

__device__ __forceinline__ void cvt8(const float* p, v8s& hi, v8s& lo){
    float4 a0 = *(const float4*)p;
    float4 a1 = *(const float4*)(p+4);
    float av[8] = {a0.x,a0.y,a0.z,a0.w,a1.x,a1.y,a1.z,a1.w};
#pragma unroll
    for (int j=0;j<8;j++){
        unsigned short h = f2bf(av[j]);
        hi[j] = (short)h;
        lo[j] = (short)f2bf(av[j] - bf2f(h));
    }
}
// reconstruct hi+lo, lrelu, re-split
__device__ __forceinline__ void lrelu_resplit(v8s hh, v8s hl, v8s& oh, v8s& ol){
#pragma unroll
    for (int j=0;j<8;j++){
        float v = bf2f((unsigned short)hh[j]) + bf2f((unsigned short)hl[j]);
        float a = lrelu(v);
        unsigned short h = f2bf(a);
        oh[j] = (short)h;
        ol[j] = (short)f2bf(a - bf2f(h));
    }
}

// ---------------- fused packing helpers ----------------
__device__ __forceinline__ void pf_item(const float* W, int K, int KB, int i,
                                        unsigned short* out){
    int l = i & 63, fb = i >> 6;
    int kb = fb % KB, nt = fb / KB;
    int n = nt*16 + (l&15);
    int k0 = kb*32 + ((l>>4)*8);
#pragma unroll
    for (int j=0;j<8;j++) out[i*8+j] = f2bf(W[(size_t)n*K + k0 + j]);
}
__device__ __forceinline__ void phl_item(const float* W, int K, int KB, int i,
                                         unsigned short* hi, unsigned short* lo){
    int l = i & 63, fb = i >> 6;
    int kb = fb % KB, nt = fb / KB;
    int n = nt*16 + (l&15);
    int k0 = kb*32 + ((l>>4)*8);
#pragma unroll
    for (int j=0;j<8;j++){
        float v = W[(size_t)n*K + k0 + j];
        unsigned short h = f2bf(v);
        hi[i*8+j] = h;
        lo[i*8+j] = f2bf(v - bf2f(h));
    }
}
__device__ __forceinline__ void pcat_item(const float* Wa, const float* Wb,
                                          int K1, int K, int KB, int i,
                                          unsigned short* out){
    int l = i & 63, fb = i >> 6;
    int kb = fb % KB, nt = fb / KB;
    int n = nt*16 + (l&15);
    int k0 = kb*32 + ((l>>4)*8);
#pragma unroll
    for (int j=0;j<8;j++){
        int k = k0 + j;
        float v = (k < K1) ? Wa[(size_t)n*K1 + k] : Wb[(size_t)n*(K-K1) + (k-K1)];
        out[i*8+j] = f2bf(v);
    }
}
__device__ __forceinline__ void pproj_item(const float* Wf, const float* Ws, int i,
                                           unsigned short* hi, unsigned short* lo){
    int l = i & 63, fb = i >> 6;
    int kb = fb & 1, nt = fb >> 1;
    int n = nt*16 + (l&15);
    int d = n >> 6, c = n & 63;
    const float* W = (d < 2) ? Wf : Ws;
    int k0 = (d&1)*64 + kb*32 + ((l>>4)*8);
#pragma unroll
    for (int j=0;j<8;j++){
        float v = W[c*130 + k0 + j];
        unsigned short h = f2bf(v);
        hi[i*8+j] = h;
        lo[i*8+j] = f2bf(v - bf2f(h));
    }
}

// ---------------- all weight prep in ONE dispatch ----------------
__global__ void pack_all(
    const float* __restrict__ gWih, const float* __restrict__ gWhh,
    const float* __restrict__ Wdyn,
    const float* __restrict__ l0Whh, const float* __restrict__ l1Wih,
    const float* __restrict__ l1Whh, const float* __restrict__ l0Wih,
    const float* __restrict__ c1Wf, const float* __restrict__ c1Ws,
    const float* __restrict__ c2Wf, const float* __restrict__ c2Ws,
    unsigned short* __restrict__ pWih, unsigned short* __restrict__ pWhh,
    unsigned short* __restrict__ pWdyn,
    unsigned short* __restrict__ B0h, unsigned short* __restrict__ B1h,
    unsigned short* __restrict__ P1h, unsigned short* __restrict__ P1l,
    unsigned short* __restrict__ P2h, unsigned short* __restrict__ P2l,
    unsigned short* __restrict__ GIh, unsigned short* __restrict__ GIl,
    int* __restrict__ cnt, int* __restrict__ gtot)
{
    int i = blockIdx.x*256 + threadIdx.x;
    if (i < 768){ pf_item(gWih, 32, 1, i, pWih); return; }   i -= 768;
    if (i < 1536){ pf_item(gWhh, 64, 2, i, pWhh); return; }  i -= 1536;
    if (i < 512){ pf_item(Wdyn, 64, 2, i, pWdyn); return; }  i -= 512;
    if (i < 8192){ pcat_item(l0Whh, l0Whh, 128, 128, 4, i, B0h); return; } i -= 8192;
    if (i < 16384){ pcat_item(l1Wih, l1Whh, 128, 256, 8, i, B1h); return; } i -= 16384;
    if (i < 2048){ pproj_item(c1Wf, c1Ws, i, P1h, P1l); return; } i -= 2048;
    if (i < 2048){ pproj_item(c2Wf, c2Ws, i, P2h, P2l); return; } i -= 2048;
    if (i < 8192){ phl_item(l0Wih, 128, 4, i, GIh, GIl); return; } i -= 8192;
    if (i < NN){ cnt[i] = 0; return; } i -= NN;
    if (i < 1){ gtot[0] = 0; return; }
}
#define PACK_TOTAL (768+1536+512+8192+16384+2048+2048+8192+NN+1)

// ---------------- GRU encoder v9: e-frags precomputed, lean t-loop (unchanged) ----------------
__global__ __launch_bounds__(256) void encoder_mfma(
    const float* __restrict__ x,
    const float* __restrict__ Wip, const float* __restrict__ bip,
    const unsigned short* __restrict__ pWih,
    const unsigned short* __restrict__ pWhh,
    const float* __restrict__ bih, const float* __restrict__ bhh,
    const unsigned short* __restrict__ pWdyn,
    const float* __restrict__ bdyn,
    float* __restrict__ hist)
{
    __shared__ float sxt[512];                                 // x transposed [t][m][c]
    __shared__ unsigned short efh[16*512], efl[16*512];        // e A-frags, all 16 steps
    __shared__ unsigned short hfh[2][1024], hfl[2][1024];      // dbuf h A-frags (swizzled)
    const int tid = threadIdx.x;
    const int l   = tid & 63;
    const int w   = tid >> 6;          // wave owns g-tile w
    const int ln  = l & 15, q = l >> 4;
    const int blk = blockIdx.x;
    const int rsw = ((l>>1)&7)<<3;     // read swizzle key

    for (int idx = tid; idx < 512; idx += 256){
        int m = idx >> 5, r = idx & 31;                        // r = t*2 + c
        sxt[(r>>1)*32 + m*2 + (r&1)] = x[(size_t)blk*512 + idx];
    }
    for (int i = tid; i < 1024; i += 256){
        hfh[0][i]=0; hfl[0][i]=0; hfh[1][i]=0; hfl[1][i]=0;
    }

    // per-lane input-projection weights for k = q*8+j (live only in prologue)
    float w0[8], w1[8], bk[8];
#pragma unroll
    for (int j = 0; j < 8; j++){
        int k = q*8 + j;
        w0[j] = Wip[2*k]; w1[j] = Wip[2*k+1]; bk[j] = bip[k];
    }
    __syncthreads();                   // sxt ready

    // ---- prologue: wave w computes e-frags for t = 4w..4w+3 ----
#pragma unroll
    for (int tt = 0; tt < 4; tt++){
        int t = w*4 + tt;
        float2 xv = *(const float2*)&sxt[t*32 + ln*2];
        v8s eh, el;
#pragma unroll
        for (int j = 0; j < 8; j++){
            float e = lrelu(w0[j]*xv.x + w1[j]*xv.y + bk[j]);
            unsigned short h_, l_;
            tsplit(e, h_, l_);
            eh[j] = (short)h_; el[j] = (short)l_;
        }
        *(v8s*)&efh[t*512 + l*8] = eh;      // b128, conflict-free
        *(v8s*)&efl[t*512 + l*8] = el;
    }

    const int c = w*16 + ln;
    const float bR  = bih[c]       + bhh[c];
    const float bZ  = bih[64 + c]  + bhh[64 + c];
    const float bNI = bih[128 + c];
    const float bNH = bhh[128 + c];
    float hprev[4] = {0.f,0.f,0.f,0.f};

    const v8s* FIH = (const v8s*)pWih;
    const v8s* FHH = (const v8s*)pWhh;
    const v8s* FDY = (const v8s*)pWdyn;
    const int wbase = (c>>5)*512 + (16*((c&31)>>3))*8 + (c&7);
    __syncthreads();                   // e-frags + h zero-init ready

    int p = 0;
#pragma unroll 1
    for (int t = 0; t < TT; t++){
        v8s eh  = *(const v8s*)&efh[t*512 + l*8];
        v8s el  = *(const v8s*)&efl[t*512 + l*8];
        v8s h0h = *(const v8s*)&hfh[p][(l*8) ^ rsw];
        v8s h0l = *(const v8s*)&hfl[p][(l*8) ^ rsw];
        v8s h1h = *(const v8s*)&hfh[p][512 + ((l*8) ^ rsw)];
        v8s h1l = *(const v8s*)&hfl[p][512 + ((l*8) ^ rsw)];

        v4f aR = {bR,bR,bR,bR};
        v4f aZ = {bZ,bZ,bZ,bZ};
        v4f aNI= {bNI,bNI,bNI,bNI};
        v4f aNH= {bNH,bNH,bNH,bNH};
        v8s b;
        b = FIH[(w   )*64 + l];    aR = MFMA16(eh,b,aR);  aR = MFMA16(el,b,aR);
        b = FHH[(w*2+0)*64+l];     aR = MFMA16(h0h,b,aR); aR = MFMA16(h0l,b,aR);
        b = FHH[(w*2+1)*64+l];     aR = MFMA16(h1h,b,aR); aR = MFMA16(h1l,b,aR);
        b = FIH[(4+w )*64 + l];    aZ = MFMA16(eh,b,aZ);  aZ = MFMA16(el,b,aZ);
        b = FHH[((4+w)*2+0)*64+l]; aZ = MFMA16(h0h,b,aZ); aZ = MFMA16(h0l,b,aZ);
        b = FHH[((4+w)*2+1)*64+l]; aZ = MFMA16(h1h,b,aZ); aZ = MFMA16(h1l,b,aZ);
        b = FIH[(8+w )*64 + l];    aNI= MFMA16(eh,b,aNI); aNI= MFMA16(el,b,aNI);
        b = FHH[((8+w)*2+0)*64+l]; aNH= MFMA16(h0h,b,aNH);aNH= MFMA16(h0l,b,aNH);
        b = FHH[((8+w)*2+1)*64+l]; aNH= MFMA16(h1h,b,aNH);aNH= MFMA16(h1l,b,aNH);

#pragma unroll
        for (int i = 0; i < 4; i++){
            float r_ = fsig(aR[i]);
            float z_ = fsig(aZ[i]);
            float nn_ = ftanh(aNI[i] + r_*aNH[i]);
            float hn = nn_ + z_*(hprev[i] - nn_);
            hprev[i] = hn;
            int row = q*4 + i;
            int off = (wbase + row*8) ^ ((((row)>>1)&7)<<3);
            unsigned short hh_, hl_;
            tsplit(hn, hh_, hl_);
            hfh[1-p][off] = hh_;
            hfl[1-p][off] = hl_;
        }
        __syncthreads();   // the ONLY barrier per step
        p ^= 1;
    }
    {
        v8s a0h,a0l,a1h,a1l;
        lrelu_resplit(*(const v8s*)&hfh[p][(l*8) ^ rsw],
                      *(const v8s*)&hfl[p][(l*8) ^ rsw],       a0h, a0l);
        lrelu_resplit(*(const v8s*)&hfh[p][512 + ((l*8) ^ rsw)],
                      *(const v8s*)&hfl[p][512 + ((l*8) ^ rsw)], a1h, a1l);
        const int nt = w;
        float bb = bdyn[nt*16 + ln];
        v4f acc = {bb,bb,bb,bb};
        v8s b;
        b = FDY[(nt*2+0)*64 + l]; acc = MFMA16(a0h,b,acc); acc = MFMA16(a0l,b,acc);
        b = FDY[(nt*2+1)*64 + l]; acc = MFMA16(a1h,b,acc); acc = MFMA16(a1l,b,acc);
#pragma unroll
        for (int i = 0; i < 4; i++){
            hist[(size_t)(blk*16 + q*4 + i)*64 + nt*16 + ln] = lrelu(acc[i]);
        }
    }
}

// ---------------- CGConv projections: MFMA (unchanged) ----------------
__global__ __launch_bounds__(256) void proj_mfma(
    const float* __restrict__ xin,
    const unsigned short* __restrict__ Bh, const unsigned short* __restrict__ Bl,
    float* __restrict__ Af, float* __restrict__ Bf,
    float* __restrict__ As, float* __restrict__ Bs)
{
    __shared__ float sx[64*68];
    const int tid = threadIdx.x;
    const int l = tid & 63;
    const int w = tid >> 6;
    const int ln = l & 15, q = l >> 4;
    const int n0 = blockIdx.x*64;

    for (int i=tid;i<64*16;i+=256){
        int nn = i>>4, f4 = i&15;
        float4 v = {0.f,0.f,0.f,0.f};
        if (n0+nn < NN) v = ((const float4*)(xin + (size_t)(n0+nn)*64))[f4];
        *(float4*)&sx[nn*68 + f4*4] = v;
    }
    __syncthreads();

    v8s ah0,al0,ah1,al1;
    cvt8(&sx[(w*16+ln)*68 +      q*8], ah0, al0);
    cvt8(&sx[(w*16+ln)*68 + 32 + q*8], ah1, al1);

    const v8s* FH = (const v8s*)Bh;
    const v8s* FL = (const v8s*)Bl;
#pragma unroll 1
    for (int nt=0; nt<16; nt++){
        v8s bh0 = FH[(nt*2+0)*64 + l], bl0 = FL[(nt*2+0)*64 + l];
        v8s bh1 = FH[(nt*2+1)*64 + l], bl1 = FL[(nt*2+1)*64 + l];
        v4f acc = {0.f,0.f,0.f,0.f};
        acc = MFMA16(ah0,bh0,acc); acc = MFMA16(al0,bh0,acc); acc = MFMA16(ah0,bl0,acc);
        acc = MFMA16(ah1,bh1,acc); acc = MFMA16(al1,bh1,acc); acc = MFMA16(ah1,bl1,acc);
        int d = nt >> 2, col = (nt&3)*16 + ln;
        float* op = (d==0) ? Af : (d==1) ? Bf : (d==2) ? As : Bs;
#pragma unroll
        for (int i=0;i<4;i++){
            int node = n0 + w*16 + q*4 + i;
            if (node < NN) op[(size_t)node*64 + col] = acc[i];
        }
    }
}

// ---------------- dst segment build: histogram + atomic alloc + scatter ----------------
__global__ void count_kernel(const int* __restrict__ ei, int* __restrict__ cnt){
    int e = blockIdx.x*256 + threadIdx.x;
    if (e < EE) atomicAdd(&cnt[ei[EE+e]], 1);
}

__global__ void alloc_kernel(const int* __restrict__ cnt, int* __restrict__ gtot,
                             int* __restrict__ off, int* __restrict__ cur){
    int n = blockIdx.x*256 + threadIdx.x;
    if (n >= NN) return;
    int c = cnt[n];
    int s = atomicAdd(gtot, c);
    off[n] = s;
    cur[n] = s;
}

// scatter + pre-gather (src, e0, e1) into ONE int4 record per edge
__global__ void scatter_kernel(const int* __restrict__ ei, const float* __restrict__ ea,
                               int* __restrict__ cur, int4* __restrict__ recS){
    int e = blockIdx.x*256 + threadIdx.x;
    if (e >= EE) return;
    int d = ei[EE+e];
    int p = atomicAdd(&cur[d], 1);
    int4 r;
    r.x = ei[e];
    r.y = __float_as_int(ea[2*(size_t)e]);
    r.z = __float_as_int(ea[2*(size_t)e+1]);
    r.w = 0;
    recS[p] = r;
}

// ---------------- CGConv aggregate (packed records) ----------------
__global__ __launch_bounds__(256) void cg_agg(
    const float* __restrict__ xin,
    const int4* __restrict__ recS,
    const int* __restrict__ off, const int* __restrict__ cnt,
    const float* __restrict__ Wf, const float* __restrict__ bf,
    const float* __restrict__ Ws, const float* __restrict__ bs,
    const float* __restrict__ Af, const float* __restrict__ Bf,
    const float* __restrict__ As, const float* __restrict__ Bs,
    const float* __restrict__ gamma, const float* __restrict__ beta,
    const float* __restrict__ mean, const float* __restrict__ var,
    float* __restrict__ outp)
{
    const int tid = threadIdx.x;
    const int c = tid & 63, wid = tid >> 6;
    const int n = blockIdx.x*4 + wid;
    if (n >= NN) return;

    const float wf0 = Wf[c*130+128], wf1 = Wf[c*130+129], bfc = bf[c];
    const float ws0 = Ws[c*130+128], ws1 = Ws[c*130+129], bsc = bs[c];
    const float afd = Af[(size_t)n*64+c] + bfc, asd = As[(size_t)n*64+c] + bsc;
    const float* Bfc = Bf + c;
    const float* Bsc = Bs + c;

    float acc = 0.f;
    int i = off[n];
    const int i1 = i + cnt[n];
#pragma unroll 1
    for (; i+1 < i1; i += 2){
        int4 r0 = recS[i], r1 = recS[i+1];
        float e00 = __int_as_float(r0.y), e01 = __int_as_float(r0.z);
        float e10 = __int_as_float(r1.y), e11 = __int_as_float(r1.z);
        float bf0v = Bfc[(size_t)r0.x*64], bs0v = Bsc[(size_t)r0.x*64];
        float bf1v = Bfc[(size_t)r1.x*64], bs1v = Bsc[(size_t)r1.x*64];
        float gf0 = afd + bf0v + wf0*e00 + wf1*e01;
        float gs0 = asd + bs0v + ws0*e00 + ws1*e01;
        float gf1 = afd + bf1v + wf0*e10 + wf1*e11;
        float gs1 = asd + bs1v + ws0*e10 + ws1*e11;
        acc += fsig(gf0)*fsoftplus(gs0);
        acc += fsig(gf1)*fsoftplus(gs1);
    }
    if (i < i1){
        int4 r0 = recS[i];
        float e00 = __int_as_float(r0.y), e01 = __int_as_float(r0.z);
        float gf = afd + Bfc[(size_t)r0.x*64] + wf0*e00 + wf1*e01;
        float gs = asd + Bsc[(size_t)r0.x*64] + ws0*e00 + ws1*e01;
        acc += fsig(gf)*fsoftplus(gs);
    }
    float bn = (acc - mean[c])*rsqrtf(var[c]+BN_EPS)*gamma[c] + beta[c];
    outp[(size_t)n*64+c] = xin[(size_t)n*64+c] + bn;
}

// ---------------- target gather + nbrs linear + concat (unchanged) ----------------
__global__ __launch_bounds__(256) void target_kernel(
    const float* __restrict__ hist, const float* __restrict__ f2,
    const int* __restrict__ tgt,
    const float* __restrict__ Wn, const float* __restrict__ bn_,
    float* __restrict__ enc)
{
    const int tid=threadIdx.x;
    const int c = tid&63, q = tid>>6;
    const int b = blockIdx.x*4 + q;
    if (b>=BB) return;
    const int n = tgt[b];
    float a = bn_[c];
#pragma unroll
    for (int k=0;k<ENC;k++) a += Wn[c*64+k]*f2[(size_t)n*64+k];
    enc[(size_t)b*128 + 64 + c] = lrelu(a);
    enc[(size_t)b*128 + c]      = hist[(size_t)n*64+c];
}

// ---------------- gi0 via MFMA (unchanged) ----------------
__global__ __launch_bounds__(512) void gi0_mfma(
    const float* __restrict__ enc,
    const unsigned short* __restrict__ GIh, const unsigned short* __restrict__ GIl,
    const float* __restrict__ bih0, const float* __restrict__ bhh0,
    float* __restrict__ gi0)
{
    __shared__ float senc[16*132];
    const int tid = threadIdx.x;
    const int l = tid & 63;
    const int w = tid >> 6;
    const int ln = l & 15, q = l >> 4;
    const int b0 = blockIdx.x*16;

    for (int i=tid;i<16*32;i+=512){
        int row = i>>5, f4 = i&31;
        *(float4*)&senc[row*132 + f4*4] = ((const float4*)(enc + (size_t)(b0+row)*128))[f4];
    }
    __syncthreads();

    v8s ah[4], al[4];
#pragma unroll
    for (int kb=0;kb<4;kb++) cvt8(&senc[ln*132 + kb*32 + q*8], ah[kb], al[kb]);

    const v8s* FH = (const v8s*)GIh;
    const v8s* FL = (const v8s*)GIl;
#pragma unroll
    for (int u=0;u<4;u++){
        int nt = w*4 + u;
        int col = nt*16 + ln;
        float bb = bih0[col] + bhh0[col];
        v4f acc = {bb,bb,bb,bb};
#pragma unroll
        for (int kb=0;kb<4;kb++){
            v8s bh = FH[(nt*4+kb)*64 + l];
            v8s bl = FL[(nt*4+kb)*64 + l];
            acc = MFMA16(ah[kb],bh,acc); acc = MFMA16(al[kb],bh,acc); acc = MFMA16(ah[kb],bl,acc);
        }
#pragma unroll
        for (int i=0;i<4;i++)
            gi0[(size_t)(b0 + q*4 + i)*512 + col] = acc[i];
    }
}

// ---------------- 2-layer LSTM decoder v9: out-proj OUT of the loop ----------------
// R17 theory: lstm at 95.6us = 9120 cyc/step with MfmaUtil 15.7 / VALUBusy 21
// / occ 10.5 (1 block/CU, LDS-capped). DS-instruction audit/wave/step: 24
// h-frag b128 reads + 16 sW0 b128 reads + 16 b16 writes + 64 __shfl_xor (DS
// cross-lane) for the out-proj = the LDS unit is the step's throughput floor.
// v9: DELETE the in-loop out-proj (64 shfl + 8 atomicAdd/step). h1new (f32)
// goes to a global scratch h1buf[b][t][j] with 4 plain dword stores; a tiny
// out_proj kernel does fut = h1buf @ Wop^T + bop afterwards. Also deletes the
// d_out memset (out_proj writes every element).
#define LMB 16
__global__ __launch_bounds__(512)
__attribute__((amdgpu_waves_per_eu(2,2)))
void lstm_mfma(
    const float* __restrict__ gi0,
    const unsigned short* __restrict__ B0h,
    const unsigned short* __restrict__ B1h,
    const float* __restrict__ bih1, const float* __restrict__ bhh1,
    float* __restrict__ h1buf)
{
    __shared__ int4 sW0[32*4*64];                                // 131072 B
    __shared__ unsigned short h0hi[2][4*512], h0lo[2][4*512];    // 16384 B
    __shared__ unsigned short h1hi[2][4*512], h1lo[2][4*512];    // 16384 B
    const int tid = threadIdx.x;
    const int l = tid & 63;
    const int w = tid >> 6;
    const int c = l & 15;
    const int q = l >> 4;
    const int j = w*16 + c;
    const int b0 = blockIdx.x*LMB;
    const int lsw = ((l>>1)&7)<<3;     // read swizzle key (row = l)

    {
        const int4* F0 = (const int4*)B0h;
        for (int i=tid;i<32*4*64;i+=512) sW0[i] = F0[i];
    }
    for (int i=tid;i<4*512;i+=512){
        h0hi[0][i]=0; h0lo[0][i]=0; h0hi[1][i]=0; h0lo[1][i]=0;
        h1hi[0][i]=0; h1lo[0][i]=0; h1hi[1][i]=0; h1lo[1][i]=0;
    }

    int4 W1r[32];
    {
        const int4* F1 = (const int4*)B1h;
#pragma unroll
        for (int g=0;g<4;g++)
#pragma unroll
            for (int kb=0;kb<8;kb++) W1r[g*8+kb] = F1[((g*8+w)*8 + kb)*64 + l];
#pragma unroll
        for (int i=0;i<32;i++)
            asm volatile("" : "+v"(W1r[i].x), "+v"(W1r[i].y), "+v"(W1r[i].z), "+v"(W1r[i].w));
    }

    float rgi[4][4];
#pragma unroll
    for (int g=0;g<4;g++)
#pragma unroll
        for (int i=0;i<4;i++)
            rgi[g][i] = gi0[(size_t)(b0 + q*4 + i)*512 + g*128 + j];

    float b1[4];
#pragma unroll
    for (int g=0;g<4;g++) b1[g] = bih1[g*128+j] + bhh1[g*128+j];
    float c0[4] = {0,0,0,0}, c1[4] = {0,0,0,0};
    const int kbw = j>>5, qw = (j>>3)&3, jw = j&7;
    __syncthreads();

    int p = 0;
#pragma unroll 1
    for (int t=0;t<OUTL;t++){
        // ---- layer 0: read h0[p], write h0[1-p]; dual hi/lo accumulators ----
        v4f aH[4], aL[4];
#pragma unroll
        for (int g=0;g<4;g++){
            v4f t4 = {rgi[g][0], rgi[g][1], rgi[g][2], rgi[g][3]};
            aH[g] = t4;
            v4f z = {0.f,0.f,0.f,0.f};
            aL[g] = z;
        }
#pragma unroll
        for (int kb=0;kb<4;kb++){
            v8s ah = *(const v8s*)&h0hi[p][kb*512 + ((l*8) ^ lsw)];
            v8s al = *(const v8s*)&h0lo[p][kb*512 + ((l*8) ^ lsw)];
#pragma unroll
            for (int g=0;g<4;g++){
                v8s bfr = as_v8s(sW0[((g*8+w)*4 + kb)*64 + l]);
                aH[g] = MFMA16(ah, bfr, aH[g]);
                aL[g] = MFMA16(al, bfr, aL[g]);
            }
        }
#pragma unroll
        for (int i=0;i<4;i++){
            float gi_ = aH[0][i]+aL[0][i], gf_ = aH[1][i]+aL[1][i];
            float gg_ = aH[2][i]+aL[2][i], go_ = aH[3][i]+aL[3][i];
            c0[i] = fsig(gf_)*c0[i] + fsig(gi_)*ftanh(gg_);
            float hn = fsig(go_)*ftanh(c0[i]);
            int row = q*4 + i;
            int off = (kbw*512 + (qw*16 + row)*8 + jw) ^ (((row>>1)&7)<<3);
            unsigned short h = f2bf(hn);
            h0hi[1-p][off] = h;
            h0lo[1-p][off] = f2bf(hn - bf2f(h));
        }
        __syncthreads();   // B1: the ONLY barrier per step

        // ---- layer 1: read h0[1-p] + h1[p], write h1[1-p] ----
        v4f bH[4], bL[4];
#pragma unroll
        for (int g=0;g<4;g++){
            v4f t4={b1[g],b1[g],b1[g],b1[g]}; bH[g]=t4;
            v4f z={0.f,0.f,0.f,0.f}; bL[g]=z;
        }
#pragma unroll
        for (int kb=0;kb<8;kb++){
            const unsigned short* hb = (kb<4) ? h0hi[1-p] : h1hi[p];
            const unsigned short* lb = (kb<4) ? h0lo[1-p] : h1lo[p];
            int kk = kb & 3;
            v8s ah = *(const v8s*)&hb[kk*512 + ((l*8) ^ lsw)];
            v8s al = *(const v8s*)&lb[kk*512 + ((l*8) ^ lsw)];
#pragma unroll
            for (int g=0;g<4;g++){
                bH[g] = MFMA16(ah, as_v8s(W1r[g*8+kb]), bH[g]);
                bL[g] = MFMA16(al, as_v8s(W1r[g*8+kb]), bL[g]);
            }
        }
        float h1new[4];
#pragma unroll
        for (int i=0;i<4;i++){
            float gi_ = bH[0][i]+bL[0][i], gf_ = bH[1][i]+bL[1][i];
            float gg_ = bH[2][i]+bL[2][i], go_ = bH[3][i]+bL[3][i];
            c1[i] = fsig(gf_)*c1[i] + fsig(gi_)*ftanh(gg_);
            h1new[i] = fsig(go_)*ftanh(c1[i]);
            int row = q*4 + i;
            int off = (kbw*512 + (qw*16 + row)*8 + jw) ^ (((row>>1)&7)<<3);
            unsigned short h = f2bf(h1new[i]);
            h1hi[1-p][off] = h;
            h1lo[1-p][off] = f2bf(h1new[i] - bf2f(h));
        }

        // ---- out-proj deferred: stream h1 (f32) to global scratch ----
#pragma unroll
        for (int i=0;i<4;i++){
            h1buf[((size_t)(b0 + q*4 + i)*OUTL + t)*DEC + j] = h1new[i];
        }
        p ^= 1;
    }
}

// ---------------- out-projection: fut = h1buf @ Wop^T + bop ----------------
// one thread per (b,t) row: 128-dot against both Wop rows; ~25.6 MB traffic.
__global__ __launch_bounds__(256) void out_proj(
    const float* __restrict__ h1buf,
    const float* __restrict__ Wop, const float* __restrict__ bop,
    float* __restrict__ outp)
{
    int idx = blockIdx.x*256 + threadIdx.x;      // idx = b*OUTL + t
    if (idx >= BB*OUTL) return;
    const float4* hp = (const float4*)(h1buf + (size_t)idx*DEC);
    const float4* w0 = (const float4*)Wop;
    const float4* w1 = (const float4*)(Wop + DEC);
    float a0 = 0.f, a1 = 0.f;
#pragma unroll
    for (int k=0;k<32;k++){
        float4 h = hp[k], x0 = w0[k], x1 = w1[k];
        a0 += h.x*x0.x + h.y*x0.y + h.z*x0.z + h.w*x0.w;
        a1 += h.x*x1.x + h.y*x1.y + h.z*x1.z + h.w*x1.w;
    }
    outp[(size_t)idx*2    ] = a0 + bop[0];
    outp[(size_t)idx*2 + 1] = a1 + bop[1];
}

extern "C" void kernel_launch(void* const* d_in, const int* in_sizes, int n_in,
                              void* d_out, int out_size, void* d_ws, size_t ws_size,
                              hipStream_t stream)
{
    const float* x    = (const float*)d_in[0];
    const int*   ei   = (const int*)d_in[1];
    const float* ea   = (const float*)d_in[2];
    const int*   tgt  = (const int*)d_in[3];
    const float* Wip  = (const float*)d_in[4];
    const float* bip  = (const float*)d_in[5];
    const float* gWih = (const float*)d_in[6];
    const float* gWhh = (const float*)d_in[7];
    const float* gbih = (const float*)d_in[8];
    const float* gbhh = (const float*)d_in[9];
    const float* Wdyn = (const float*)d_in[10];
    const float* bdyn = (const float*)d_in[11];
    const float* c1Wf=(const float*)d_in[12]; const float* c1bf=(const float*)d_in[13];
    const float* c1Ws=(const float*)d_in[14]; const float* c1bs=(const float*)d_in[15];
    const float* c1g =(const float*)d_in[16]; const float* c1b =(const float*)d_in[17];
    const float* c1m =(const float*)d_in[18]; const float* c1v =(const float*)d_in[19];
    const float* c2Wf=(const float*)d_in[20]; const float* c2bf=(const float*)d_in[21];
    const float* c2Ws=(const float*)d_in[22]; const float* c2bs=(const float*)d_in[23];
    const float* c2g =(const float*)d_in[24]; const float* c2b =(const float*)d_in[25];
    const float* c2m =(const float*)d_in[26]; const float* c2v =(const float*)d_in[27];
    const float* Wn  =(const float*)d_in[28]; const float* bn_ =(const float*)d_in[29];
    const float* l0Wih=(const float*)d_in[30]; const float* l0Whh=(const float*)d_in[31];
    const float* l0bih=(const float*)d_in[32]; const float* l0bhh=(const float*)d_in[33];
    const float* l1Wih=(const float*)d_in[34]; const float* l1Whh=(const float*)d_in[35];
    const float* l1bih=(const float*)d_in[36]; const float* l1bhh=(const float*)d_in[37];
    const float* Wop =(const float*)d_in[38]; const float* bop=(const float*)d_in[39];

    float* ws = (float*)d_ws;
    size_t o = 0;
    float* hist = ws + o; o += (size_t)NN*ENC;
    float* f1   = ws + o; o += (size_t)NN*ENC;
    float* f2   = ws + o; o += (size_t)NN*ENC;
    float* Af   = ws + o; o += (size_t)NN*ENC;
    float* Bf   = ws + o; o += (size_t)NN*ENC;
    float* As   = ws + o; o += (size_t)NN*ENC;
    float* Bs   = ws + o; o += (size_t)NN*ENC;
    float* enc  = ws + o; o += (size_t)BB*2*ENC;
    float* gi0  = ws + o; o += (size_t)BB*4*DEC;
    unsigned short* pWih  = (unsigned short*)(ws + o); o += (size_t)12*64*8/2;
    unsigned short* pWhh  = (unsigned short*)(ws + o); o += (size_t)24*64*8/2;
    unsigned short* pWdyn = (unsigned short*)(ws + o); o += (size_t)8*64*8/2;
    unsigned short* B0h = (unsigned short*)(ws + o); o += (size_t)32*4*64*8/2;
    unsigned short* B1h = (unsigned short*)(ws + o); o += (size_t)32*8*64*8/2;
    unsigned short* P1h = (unsigned short*)(ws + o); o += (size_t)2048*8/2;
    unsigned short* P1l = (unsigned short*)(ws + o); o += (size_t)2048*8/2;
    unsigned short* P2h = (unsigned short*)(ws + o); o += (size_t)2048*8/2;
    unsigned short* P2l = (unsigned short*)(ws + o); o += (size_t)2048*8/2;
    unsigned short* GIh = (unsigned short*)(ws + o); o += (size_t)8192*8/2;
    unsigned short* GIl = (unsigned short*)(ws + o); o += (size_t)8192*8/2;
    int* cnt    = (int*)(ws + o); o += NN;
    int* offv   = (int*)(ws + o); o += NN+1;
    int* curv   = (int*)(ws + o); o += NN;
    int* gtot   = (int*)(ws + o); o += 1;
    o = (o + 3) & ~(size_t)3;               // align to 16B for int4 records
    int4* recS  = (int4*)(ws + o); o += (size_t)4*EE;

    // h1buf (BB*OUTL*DEC = 6.4M floats) aliases Af..Bf (2*NN*ENC = 6.4M floats):
    // Af/Bf are dead after cg_agg #2, which completes (stream-ordered) before
    // lstm_mfma runs.
    float* h1buf = Af;

    // --- all weight prep + cnt/gtot zero in one dispatch ---
    pack_all<<<(PACK_TOTAL+255)/256, 256, 0, stream>>>(
        gWih, gWhh, Wdyn, l0Whh, l1Wih, l1Whh, l0Wih,
        c1Wf, c1Ws, c2Wf, c2Ws,
        pWih, pWhh, pWdyn, B0h, B1h, P1h, P1l, P2h, P2l, GIh, GIl, cnt, gtot);

    // --- dst segment build (order-free atomic allocation) ---
    count_kernel<<<(EE+255)/256, 256, 0, stream>>>(ei, cnt);
    alloc_kernel<<<(NN+255)/256, 256, 0, stream>>>(cnt, gtot, offv, curv);
    scatter_kernel<<<(EE+255)/256, 256, 0, stream>>>(ei, ea, curv, recS);

    // --- history encoder (MFMA, e-frag precompute prologue) ---
    encoder_mfma<<<NN/16, 256, 0, stream>>>(x, Wip, bip, pWih, pWhh, gbih, gbhh, pWdyn, bdyn, hist);

    // --- CGConv 1 ---
    proj_mfma<<<(NN+63)/64, 256, 0, stream>>>(hist, P1h, P1l, Af,Bf,As,Bs);
    cg_agg<<<(NN+3)/4, 256, 0, stream>>>(hist, recS, offv, cnt,
                                         c1Wf,c1bf,c1Ws,c1bs, Af,Bf,As,Bs,
                                         c1g,c1b,c1m,c1v, f1);

    // --- CGConv 2 ---
    proj_mfma<<<(NN+63)/64, 256, 0, stream>>>(f1, P2h, P2l, Af,Bf,As,Bs);
    cg_agg<<<(NN+3)/4, 256, 0, stream>>>(f1, recS, offv, cnt,
                                         c2Wf,c2bf,c2Ws,c2bs, Af,Bf,As,Bs,
                                         c2g,c2b,c2m,c2v, f2);

    // --- target encoding ---
    target_kernel<<<(BB+3)/4, 256, 0, stream>>>(hist, f2, tgt, Wn, bn_, enc);

    // --- LSTM decoder prep (MFMA gi0) ---
    gi0_mfma<<<BB/16, 512, 0, stream>>>(enc, GIh, GIl, l0bih, l0bhh, gi0);

    // --- LSTM decoder (out-proj deferred to scratch) ---
    lstm_mfma<<<BB/LMB, 512, 0, stream>>>(gi0, B0h, B1h,
                                          l1bih, l1bhh, h1buf);

    // --- out-projection ---
    out_proj<<<(BB*OUTL+255)/256, 256, 0, stream>>>(h1buf, Wop, bop, (float*)d_out);
}

// Round 7
// 588.920 us; speedup vs baseline: 1.0678x; 1.0183x over previous
//
#include <hip/hip_runtime.h>
#include <math.h>

#define NN   50000
#define TT   16
#define EE   800000
#define BB   2000
#define EMBD 32
#define ENC  64
#define DEC  128
#define OUTL 25
#define BN_EPS 1e-5f

typedef short v8s __attribute__((ext_vector_type(8)));
typedef float v4f __attribute__((ext_vector_type(4)));
#define MFMA16(a,b,c) __builtin_amdgcn_mfma_f32_16x16x32_bf16((a),(b),(c),0,0,0)

__device__ __forceinline__ float lrelu(float v){ return v >= 0.f ? v : 0.1f*v; }
__device__ __forceinline__ float fsig(float v){ return __builtin_amdgcn_rcpf(1.f + __expf(-v)); }
__device__ __forceinline__ float ftanh(float v){ return 2.f*__builtin_amdgcn_rcpf(1.f + __expf(-2.f*v)) - 1.f; }
__device__ __forceinline__ float fsoftplus(float v){
    return v > 15.f ? v : __logf(1.f + __expf(v));
}
__device__ __forceinline__ float hsum(float4 a){ return (a.x+a.y)+(a.z+a.w); }

__device__ __forceinline__ unsigned short f2bf(float f){
    unsigned u = __float_as_uint(f);
    u = u + 0x7FFFu + ((u>>16)&1u);
    return (unsigned short)(u>>16);
}
__device__ __forceinline__ float bf2f(unsigned short s){ return __uint_as_float(((unsigned)s)<<16); }

// truncation-based hi/lo split (R12): hi = truncated bf16, lo = bf16 of the
// exact residual; ~4 VALU ops vs ~8 for the RNE pair, same net precision.
__device__ __forceinline__ void tsplit(float v, unsigned short& hi, unsigned short& lo){
    unsigned u = __float_as_uint(v);
    hi = (unsigned short)(u >> 16);
    float r = v - __uint_as_float(u & 0xFFFF0000u);
    lo = (unsigned short)(__float_as_uint(r) >> 16);
}

__device__ __forceinline__ v8s as_v8s(int4 v){
    union { int4 i; v8s s; } u; u.i = v; return u.s;
}

__device__ __forceinline__ void cvt8(const float* p, v8s& hi, v8s& lo){
    float4 a0 = *(const float4*)p;
    float4 a1 = *(const float4*)(p+4);
    float av[8] = {a0.x,a0.y,a0.z,a0.w,a1.x,a1.y,a1.z,a1.w};
#pragma unroll
    for (int j=0;j<8;j++){
        unsigned short h = f2bf(av[j]);
        hi[j] = (short)h;
        lo[j] = (short)f2bf(av[j] - bf2f(h));
    }
}
// reconstruct hi+lo, lrelu, re-split
__device__ __forceinline__ void lrelu_resplit(v8s hh, v8s hl, v8s& oh, v8s& ol){
#pragma unroll
    for (int j=0;j<8;j++){
        float v = bf2f((unsigned short)hh[j]) + bf2f((unsigned short)hl[j]);
        float a = lrelu(v);
        unsigned short h = f2bf(a);
        oh[j] = (short)h;
        ol[j] = (short)f2bf(a - bf2f(h));
    }
}

// ---------------- fused packing helpers ----------------
__device__ __forceinline__ void pf_item(const float* W, int K, int KB, int i,
                                        unsigned short* out){
    int l = i & 63, fb = i >> 6;
    int kb = fb % KB, nt = fb / KB;
    int n = nt*16 + (l&15);
    int k0 = kb*32 + ((l>>4)*8);
#pragma unroll
    for (int j=0;j<8;j++) out[i*8+j] = f2bf(W[(size_t)n*K + k0 + j]);
}
__device__ __forceinline__ void phl_item(const float* W, int K, int KB, int i,
                                         unsigned short* hi, unsigned short* lo){
    int l = i & 63, fb = i >> 6;
    int kb = fb % KB, nt = fb / KB;
    int n = nt*16 + (l&15);
    int k0 = kb*32 + ((l>>4)*8);
#pragma unroll
    for (int j=0;j<8;j++){
        float v = W[(size_t)n*K + k0 + j];
        unsigned short h = f2bf(v);
        hi[i*8+j] = h;
        lo[i*8+j] = f2bf(v - bf2f(h));
    }
}
__device__ __forceinline__ void pcat_item(const float* Wa, const float* Wb,
                                          int K1, int K, int KB, int i,
                                          unsigned short* out){
    int l = i & 63, fb = i >> 6;
    int kb = fb % KB, nt = fb / KB;
    int n = nt*16 + (l&15);
    int k0 = kb*32 + ((l>>4)*8);
#pragma unroll
    for (int j=0;j<8;j++){
        int k = k0 + j;
        float v = (k < K1) ? Wa[(size_t)n*K1 + k] : Wb[(size_t)n*(K-K1) + (k-K1)];
        out[i*8+j] = f2bf(v);
    }
}
__device__ __forceinline__ void pproj_item(const float* Wf, const float* Ws, int i,
                                           unsigned short* hi, unsigned short* lo){
    int l = i & 63, fb = i >> 6;
    int kb = fb & 1, nt = fb >> 1;
    int n = nt*16 + (l&15);
    int d = n >> 6, c = n & 63;
    const float* W = (d < 2) ? Wf : Ws;
    int k0 = (d&1)*64 + kb*32 + ((l>>4)*8);
#pragma unroll
    for (int j=0;j<8;j++){
        float v = W[c*130 + k0 + j];
        unsigned short h = f2bf(v);
        hi[i*8+j] = h;
        lo[i*8+j] = f2bf(v - bf2f(h));
    }
}

// ---------------- all weight prep in ONE dispatch ----------------
__global__ void pack_all(
    const float* __restrict__ gWih, const float* __restrict__ gWhh,
    const float* __restrict__ Wdyn,
    const float* __restrict__ l0Whh, const float* __restrict__ l1Wih,
    const float* __restrict__ l1Whh, const float* __restrict__ l0Wih,
    const float* __restrict__ c1Wf, const float* __restrict__ c1Ws,
    const float* __restrict__ c2Wf, const float* __restrict__ c2Ws,
    unsigned short* __restrict__ pWih, unsigned short* __restrict__ pWhh,
    unsigned short* __restrict__ pWdyn,
    unsigned short* __restrict__ B0h, unsigned short* __restrict__ B1h,
    unsigned short* __restrict__ P1h, unsigned short* __restrict__ P1l,
    unsigned short* __restrict__ P2h, unsigned short* __restrict__ P2l,
    unsigned short* __restrict__ GIh, unsigned short* __restrict__ GIl,
    int* __restrict__ cnt, int* __restrict__ gtot)
{
    int i = blockIdx.x*256 + threadIdx.x;
    if (i < 768){ pf_item(gWih, 32, 1, i, pWih); return; }   i -= 768;
    if (i < 1536){ pf_item(gWhh, 64, 2, i, pWhh); return; }  i -= 1536;
    if (i < 512){ pf_item(Wdyn, 64, 2, i, pWdyn); return; }  i -= 512;
    if (i < 8192){ pcat_item(l0Whh, l0Whh, 128, 128, 4, i, B0h); return; } i -= 8192;
    if (i < 16384){ pcat_item(l1Wih, l1Whh, 128, 256, 8, i, B1h); return; } i -= 16384;
    if (i < 2048){ pproj_item(c1Wf, c1Ws, i, P1h, P1l); return; } i -= 2048;
    if (i < 2048){ pproj_item(c2Wf, c2Ws, i, P2h, P2l); return; } i -= 2048;
    if (i < 8192){ phl_item(l0Wih, 128, 4, i, GIh, GIl); return; } i -= 8192;
    if (i < NN){ cnt[i] = 0; return; } i -= NN;
    if (i < 1){ gtot[0] = 0; return; }
}
#define PACK_TOTAL (768+1536+512+8192+16384+2048+2048+8192+NN+1)

// ---------------- GRU encoder v10: 40KB LDS -> 4 blocks/CU ----------------
// R18: v9 at 95.5us, VALUBusy 63, occ 27.8% with LDS 43008 (3 blocks/CU cap).
// The sxt staging buffer (2KB) is the difference between 3 and 4 blocks/CU:
// efh/efl 32KB + hfh/hfl 8KB = 40960 B exactly -> 4 blocks x 40960 = 160KiB.
// sxt is droppable: each lane's prologue x-read is a direct global float2 at
// x[(blk*16+ln)*32 + t*2] (4 loads/lane, prologue-only, broadcast across q).
// Bit-identical numerics; one pre-loop barrier also deleted.
__global__ __launch_bounds__(256) void encoder_mfma(
    const float* __restrict__ x,
    const float* __restrict__ Wip, const float* __restrict__ bip,
    const unsigned short* __restrict__ pWih,
    const unsigned short* __restrict__ pWhh,
    const float* __restrict__ bih, const float* __restrict__ bhh,
    const unsigned short* __restrict__ pWdyn,
    const float* __restrict__ bdyn,
    float* __restrict__ hist)
{
    __shared__ unsigned short efh[16*512], efl[16*512];        // e A-frags, all 16 steps
    __shared__ unsigned short hfh[2][1024], hfl[2][1024];      // dbuf h A-frags (swizzled)
    const int tid = threadIdx.x;
    const int l   = tid & 63;
    const int w   = tid >> 6;          // wave owns g-tile w
    const int ln  = l & 15, q = l >> 4;
    const int blk = blockIdx.x;
    const int rsw = ((l>>1)&7)<<3;     // read swizzle key

    for (int i = tid; i < 1024; i += 256){
        hfh[0][i]=0; hfl[0][i]=0; hfh[1][i]=0; hfl[1][i]=0;
    }

    // per-lane input-projection weights for k = q*8+j (live only in prologue)
    float w0[8], w1[8], bk[8];
#pragma unroll
    for (int j = 0; j < 8; j++){
        int k = q*8 + j;
        w0[j] = Wip[2*k]; w1[j] = Wip[2*k+1]; bk[j] = bip[k];
    }

    // ---- prologue: wave w computes e-frags for t = 4w..4w+3 ----
    // direct global float2 per (node=ln, t); 4-lane broadcast across q.
    const float2* xrow = (const float2*)(x + (size_t)(blk*16 + ln)*32);
#pragma unroll
    for (int tt = 0; tt < 4; tt++){
        int t = w*4 + tt;
        float2 xv = xrow[t];
        v8s eh, el;
#pragma unroll
        for (int j = 0; j < 8; j++){
            float e = lrelu(w0[j]*xv.x + w1[j]*xv.y + bk[j]);
            unsigned short h_, l_;
            tsplit(e, h_, l_);
            eh[j] = (short)h_; el[j] = (short)l_;
        }
        *(v8s*)&efh[t*512 + l*8] = eh;      // b128, conflict-free
        *(v8s*)&efl[t*512 + l*8] = el;
    }

    const int c = w*16 + ln;
    const float bR  = bih[c]       + bhh[c];
    const float bZ  = bih[64 + c]  + bhh[64 + c];
    const float bNI = bih[128 + c];
    const float bNH = bhh[128 + c];
    float hprev[4] = {0.f,0.f,0.f,0.f};

    const v8s* FIH = (const v8s*)pWih;
    const v8s* FHH = (const v8s*)pWhh;
    const v8s* FDY = (const v8s*)pWdyn;
    const int wbase = (c>>5)*512 + (16*((c&31)>>3))*8 + (c&7);
    __syncthreads();                   // e-frags + h zero-init ready

    int p = 0;
#pragma unroll 1
    for (int t = 0; t < TT; t++){
        v8s eh  = *(const v8s*)&efh[t*512 + l*8];
        v8s el  = *(const v8s*)&efl[t*512 + l*8];
        v8s h0h = *(const v8s*)&hfh[p][(l*8) ^ rsw];
        v8s h0l = *(const v8s*)&hfl[p][(l*8) ^ rsw];
        v8s h1h = *(const v8s*)&hfh[p][512 + ((l*8) ^ rsw)];
        v8s h1l = *(const v8s*)&hfl[p][512 + ((l*8) ^ rsw)];

        v4f aR = {bR,bR,bR,bR};
        v4f aZ = {bZ,bZ,bZ,bZ};
        v4f aNI= {bNI,bNI,bNI,bNI};
        v4f aNH= {bNH,bNH,bNH,bNH};
        v8s b;
        b = FIH[(w   )*64 + l];    aR = MFMA16(eh,b,aR);  aR = MFMA16(el,b,aR);
        b = FHH[(w*2+0)*64+l];     aR = MFMA16(h0h,b,aR); aR = MFMA16(h0l,b,aR);
        b = FHH[(w*2+1)*64+l];     aR = MFMA16(h1h,b,aR); aR = MFMA16(h1l,b,aR);
        b = FIH[(4+w )*64 + l];    aZ = MFMA16(eh,b,aZ);  aZ = MFMA16(el,b,aZ);
        b = FHH[((4+w)*2+0)*64+l]; aZ = MFMA16(h0h,b,aZ); aZ = MFMA16(h0l,b,aZ);
        b = FHH[((4+w)*2+1)*64+l]; aZ = MFMA16(h1h,b,aZ); aZ = MFMA16(h1l,b,aZ);
        b = FIH[(8+w )*64 + l];    aNI= MFMA16(eh,b,aNI); aNI= MFMA16(el,b,aNI);
        b = FHH[((8+w)*2+0)*64+l]; aNH= MFMA16(h0h,b,aNH);aNH= MFMA16(h0l,b,aNH);
        b = FHH[((8+w)*2+1)*64+l]; aNH= MFMA16(h1h,b,aNH);aNH= MFMA16(h1l,b,aNH);

#pragma unroll
        for (int i = 0; i < 4; i++){
            float r_ = fsig(aR[i]);
            float z_ = fsig(aZ[i]);
            float nn_ = ftanh(aNI[i] + r_*aNH[i]);
            float hn = nn_ + z_*(hprev[i] - nn_);
            hprev[i] = hn;
            int row = q*4 + i;
            int off = (wbase + row*8) ^ ((((row)>>1)&7)<<3);
            unsigned short hh_, hl_;
            tsplit(hn, hh_, hl_);
            hfh[1-p][off] = hh_;
            hfl[1-p][off] = hl_;
        }
        __syncthreads();   // the ONLY barrier per step
        p ^= 1;
    }
    {
        v8s a0h,a0l,a1h,a1l;
        lrelu_resplit(*(const v8s*)&hfh[p][(l*8) ^ rsw],
                      *(const v8s*)&hfl[p][(l*8) ^ rsw],       a0h, a0l);
        lrelu_resplit(*(const v8s*)&hfh[p][512 + ((l*8) ^ rsw)],
                      *(const v8s*)&hfl[p][512 + ((l*8) ^ rsw)], a1h, a1l);
        const int nt = w;
        float bb = bdyn[nt*16 + ln];
        v4f acc = {bb,bb,bb,bb};
        v8s b;
        b = FDY[(nt*2+0)*64 + l]; acc = MFMA16(a0h,b,acc); acc = MFMA16(a0l,b,acc);
        b = FDY[(nt*2+1)*64 + l]; acc = MFMA16(a1h,b,acc); acc = MFMA16(a1l,b,acc);
#pragma unroll
        for (int i = 0; i < 4; i++){
            hist[(size_t)(blk*16 + q*4 + i)*64 + nt*16 + ln] = lrelu(acc[i]);
        }
    }
}

// ---------------- CGConv projections: MFMA (unchanged) ----------------
__global__ __launch_bounds__(256) void proj_mfma(
    const float* __restrict__ xin,
    const unsigned short* __restrict__ Bh, const unsigned short* __restrict__ Bl,
    float* __restrict__ Af, float* __restrict__ Bf,
    float* __restrict__ As, float* __restrict__ Bs)
{
    __shared__ float sx[64*68];
    const int tid = threadIdx.x;
    const int l = tid & 63;
    const int w = tid >> 6;
    const int ln = l & 15, q = l >> 4;
    const int n0 = blockIdx.x*64;

    for (int i=tid;i<64*16;i+=256){
        int nn = i>>4, f4 = i&15;
        float4 v = {0.f,0.f,0.f,0.f};
        if (n0+nn < NN) v = ((const float4*)(xin + (size_t)(n0+nn)*64))[f4];
        *(float4*)&sx[nn*68 + f4*4] = v;
    }
    __syncthreads();

    v8s ah0,al0,ah1,al1;
    cvt8(&sx[(w*16+ln)*68 +      q*8], ah0, al0);
    cvt8(&sx[(w*16+ln)*68 + 32 + q*8], ah1, al1);

    const v8s* FH = (const v8s*)Bh;
    const v8s* FL = (const v8s*)Bl;
#pragma unroll 1
    for (int nt=0; nt<16; nt++){
        v8s bh0 = FH[(nt*2+0)*64 + l], bl0 = FL[(nt*2+0)*64 + l];
        v8s bh1 = FH[(nt*2+1)*64 + l], bl1 = FL[(nt*2+1)*64 + l];
        v4f acc = {0.f,0.f,0.f,0.f};
        acc = MFMA16(ah0,bh0,acc); acc = MFMA16(al0,bh0,acc); acc = MFMA16(ah0,bl0,acc);
        acc = MFMA16(ah1,bh1,acc); acc = MFMA16(al1,bh1,acc); acc = MFMA16(ah1,bl1,acc);
        int d = nt >> 2, col = (nt&3)*16 + ln;
        float* op = (d==0) ? Af : (d==1) ? Bf : (d==2) ? As : Bs;
#pragma unroll
        for (int i=0;i<4;i++){
            int node = n0 + w*16 + q*4 + i;
            if (node < NN) op[(size_t)node*64 + col] = acc[i];
        }
    }
}

// ---------------- dst segment build: histogram + atomic alloc + scatter ----------------
__global__ void count_kernel(const int* __restrict__ ei, int* __restrict__ cnt){
    int e = blockIdx.x*256 + threadIdx.x;
    if (e < EE) atomicAdd(&cnt[ei[EE+e]], 1);
}

__global__ void alloc_kernel(const int* __restrict__ cnt, int* __restrict__ gtot,
                             int* __restrict__ off, int* __restrict__ cur){
    int n = blockIdx.x*256 + threadIdx.x;
    if (n >= NN) return;
    int c = cnt[n];
    int s = atomicAdd(gtot, c);
    off[n] = s;
    cur[n] = s;
}

// scatter + pre-gather (src, e0, e1) into ONE int4 record per edge
__global__ void scatter_kernel(const int* __restrict__ ei, const float* __restrict__ ea,
                               int* __restrict__ cur, int4* __restrict__ recS){
    int e = blockIdx.x*256 + threadIdx.x;
    if (e >= EE) return;
    int d = ei[EE+e];
    int p = atomicAdd(&cur[d], 1);
    int4 r;
    r.x = ei[e];
    r.y = __float_as_int(ea[2*(size_t)e]);
    r.z = __float_as_int(ea[2*(size_t)e+1]);
    r.w = 0;
    recS[p] = r;
}

// ---------------- CGConv aggregate (packed records) ----------------
__global__ __launch_bounds__(256) void cg_agg(
    const float* __restrict__ xin,
    const int4* __restrict__ recS,
    const int* __restrict__ off, const int* __restrict__ cnt,
    const float* __restrict__ Wf, const float* __restrict__ bf,
    const float* __restrict__ Ws, const float* __restrict__ bs,
    const float* __restrict__ Af, const float* __restrict__ Bf,
    const float* __restrict__ As, const float* __restrict__ Bs,
    const float* __restrict__ gamma, const float* __restrict__ beta,
    const float* __restrict__ mean, const float* __restrict__ var,
    float* __restrict__ outp)
{
    const int tid = threadIdx.x;
    const int c = tid & 63, wid = tid >> 6;
    const int n = blockIdx.x*4 + wid;
    if (n >= NN) return;

    const float wf0 = Wf[c*130+128], wf1 = Wf[c*130+129], bfc = bf[c];
    const float ws0 = Ws[c*130+128], ws1 = Ws[c*130+129], bsc = bs[c];
    const float afd = Af[(size_t)n*64+c] + bfc, asd = As[(size_t)n*64+c] + bsc;
    const float* Bfc = Bf + c;
    const float* Bsc = Bs + c;

    float acc = 0.f;
    int i = off[n];
    const int i1 = i + cnt[n];
#pragma unroll 1
    for (; i+1 < i1; i += 2){
        int4 r0 = recS[i], r1 = recS[i+1];
        float e00 = __int_as_float(r0.y), e01 = __int_as_float(r0.z);
        float e10 = __int_as_float(r1.y), e11 = __int_as_float(r1.z);
        float bf0v = Bfc[(size_t)r0.x*64], bs0v = Bsc[(size_t)r0.x*64];
        float bf1v = Bfc[(size_t)r1.x*64], bs1v = Bsc[(size_t)r1.x*64];
        float gf0 = afd + bf0v + wf0*e00 + wf1*e01;
        float gs0 = asd + bs0v + ws0*e00 + ws1*e01;
        float gf1 = afd + bf1v + wf0*e10 + wf1*e11;
        float gs1 = asd + bs1v + ws0*e10 + ws1*e11;
        acc += fsig(gf0)*fsoftplus(gs0);
        acc += fsig(gf1)*fsoftplus(gs1);
    }
    if (i < i1){
        int4 r0 = recS[i];
        float e00 = __int_as_float(r0.y), e01 = __int_as_float(r0.z);
        float gf = afd + Bfc[(size_t)r0.x*64] + wf0*e00 + wf1*e01;
        float gs = asd + Bsc[(size_t)r0.x*64] + ws0*e00 + ws1*e01;
        acc += fsig(gf)*fsoftplus(gs);
    }
    float bn = (acc - mean[c])*rsqrtf(var[c]+BN_EPS)*gamma[c] + beta[c];
    outp[(size_t)n*64+c] = xin[(size_t)n*64+c] + bn;
}

// ---------------- target gather + nbrs linear + concat (unchanged) ----------------
__global__ __launch_bounds__(256) void target_kernel(
    const float* __restrict__ hist, const float* __restrict__ f2,
    const int* __restrict__ tgt,
    const float* __restrict__ Wn, const float* __restrict__ bn_,
    float* __restrict__ enc)
{
    const int tid=threadIdx.x;
    const int c = tid&63, q = tid>>6;
    const int b = blockIdx.x*4 + q;
    if (b>=BB) return;
    const int n = tgt[b];
    float a = bn_[c];
#pragma unroll
    for (int k=0;k<ENC;k++) a += Wn[c*64+k]*f2[(size_t)n*64+k];
    enc[(size_t)b*128 + 64 + c] = lrelu(a);
    enc[(size_t)b*128 + c]      = hist[(size_t)n*64+c];
}

// ---------------- gi0 via MFMA (unchanged) ----------------
__global__ __launch_bounds__(512) void gi0_mfma(
    const float* __restrict__ enc,
    const unsigned short* __restrict__ GIh, const unsigned short* __restrict__ GIl,
    const float* __restrict__ bih0, const float* __restrict__ bhh0,
    float* __restrict__ gi0)
{
    __shared__ float senc[16*132];
    const int tid = threadIdx.x;
    const int l = tid & 63;
    const int w = tid >> 6;
    const int ln = l & 15, q = l >> 4;
    const int b0 = blockIdx.x*16;

    for (int i=tid;i<16*32;i+=512){
        int row = i>>5, f4 = i&31;
        *(float4*)&senc[row*132 + f4*4] = ((const float4*)(enc + (size_t)(b0+row)*128))[f4];
    }
    __syncthreads();

    v8s ah[4], al[4];
#pragma unroll
    for (int kb=0;kb<4;kb++) cvt8(&senc[ln*132 + kb*32 + q*8], ah[kb], al[kb]);

    const v8s* FH = (const v8s*)GIh;
    const v8s* FL = (const v8s*)GIl;
#pragma unroll
    for (int u=0;u<4;u++){
        int nt = w*4 + u;
        int col = nt*16 + ln;
        float bb = bih0[col] + bhh0[col];
        v4f acc = {bb,bb,bb,bb};
#pragma unroll
        for (int kb=0;kb<4;kb++){
            v8s bh = FH[(nt*4+kb)*64 + l];
            v8s bl = FL[(nt*4+kb)*64 + l];
            acc = MFMA16(ah[kb],bh,acc); acc = MFMA16(al[kb],bh,acc); acc = MFMA16(ah[kb],bl,acc);
        }
#pragma unroll
        for (int i=0;i<4;i++)
            gi0[(size_t)(b0 + q*4 + i)*512 + col] = acc[i];
    }
}

// ---------------- 2-layer LSTM decoder v9: out-proj OUT of the loop (unchanged) ----------------
#define LMB 16
__global__ __launch_bounds__(512)
__attribute__((amdgpu_waves_per_eu(2,2)))
void lstm_mfma(
    const float* __restrict__ gi0,
    const unsigned short* __restrict__ B0h,
    const unsigned short* __restrict__ B1h,
    const float* __restrict__ bih1, const float* __restrict__ bhh1,
    float* __restrict__ h1buf)
{
    __shared__ int4 sW0[32*4*64];                                // 131072 B
    __shared__ unsigned short h0hi[2][4*512], h0lo[2][4*512];    // 16384 B
    __shared__ unsigned short h1hi[2][4*512], h1lo[2][4*512];    // 16384 B
    const int tid = threadIdx.x;
    const int l = tid & 63;
    const int w = tid >> 6;
    const int c = l & 15;
    const int q = l >> 4;
    const int j = w*16 + c;
    const int b0 = blockIdx.x*LMB;
    const int lsw = ((l>>1)&7)<<3;     // read swizzle key (row = l)

    {
        const int4* F0 = (const int4*)B0h;
        for (int i=tid;i<32*4*64;i+=512) sW0[i] = F0[i];
    }
    for (int i=tid;i<4*512;i+=512){
        h0hi[0][i]=0; h0lo[0][i]=0; h0hi[1][i]=0; h0lo[1][i]=0;
        h1hi[0][i]=0; h1lo[0][i]=0; h1hi[1][i]=0; h1lo[1][i]=0;
    }

    int4 W1r[32];
    {
        const int4* F1 = (const int4*)B1h;
#pragma unroll
        for (int g=0;g<4;g++)
#pragma unroll
            for (int kb=0;kb<8;kb++) W1r[g*8+kb] = F1[((g*8+w)*8 + kb)*64 + l];
#pragma unroll
        for (int i=0;i<32;i++)
            asm volatile("" : "+v"(W1r[i].x), "+v"(W1r[i].y), "+v"(W1r[i].z), "+v"(W1r[i].w));
    }

    float rgi[4][4];
#pragma unroll
    for (int g=0;g<4;g++)
#pragma unroll
        for (int i=0;i<4;i++)
            rgi[g][i] = gi0[(size_t)(b0 + q*4 + i)*512 + g*128 + j];

    float b1[4];
#pragma unroll
    for (int g=0;g<4;g++) b1[g] = bih1[g*128+j] + bhh1[g*128+j];
    float c0[4] = {0,0,0,0}, c1[4] = {0,0,0,0};
    const int kbw = j>>5, qw = (j>>3)&3, jw = j&7;
    __syncthreads();

    int p = 0;
#pragma unroll 1
    for (int t=0;t<OUTL;t++){
        // ---- layer 0: read h0[p], write h0[1-p]; dual hi/lo accumulators ----
        v4f aH[4], aL[4];
#pragma unroll
        for (int g=0;g<4;g++){
            v4f t4 = {rgi[g][0], rgi[g][1], rgi[g][2], rgi[g][3]};
            aH[g] = t4;
            v4f z = {0.f,0.f,0.f,0.f};
            aL[g] = z;
        }
#pragma unroll
        for (int kb=0;kb<4;kb++){
            v8s ah = *(const v8s*)&h0hi[p][kb*512 + ((l*8) ^ lsw)];
            v8s al = *(const v8s*)&h0lo[p][kb*512 + ((l*8) ^ lsw)];
#pragma unroll
            for (int g=0;g<4;g++){
                v8s bfr = as_v8s(sW0[((g*8+w)*4 + kb)*64 + l]);
                aH[g] = MFMA16(ah, bfr, aH[g]);
                aL[g] = MFMA16(al, bfr, aL[g]);
            }
        }
#pragma unroll
        for (int i=0;i<4;i++){
            float gi_ = aH[0][i]+aL[0][i], gf_ = aH[1][i]+aL[1][i];
            float gg_ = aH[2][i]+aL[2][i], go_ = aH[3][i]+aL[3][i];
            c0[i] = fsig(gf_)*c0[i] + fsig(gi_)*ftanh(gg_);
            float hn = fsig(go_)*ftanh(c0[i]);
            int row = q*4 + i;
            int off = (kbw*512 + (qw*16 + row)*8 + jw) ^ (((row>>1)&7)<<3);
            unsigned short h = f2bf(hn);
            h0hi[1-p][off] = h;
            h0lo[1-p][off] = f2bf(hn - bf2f(h));
        }
        __syncthreads();   // B1: the ONLY barrier per step

        // ---- layer 1: read h0[1-p] + h1[p], write h1[1-p] ----
        v4f bH[4], bL[4];
#pragma unroll
        for (int g=0;g<4;g++){
            v4f t4={b1[g],b1[g],b1[g],b1[g]}; bH[g]=t4;
            v4f z={0.f,0.f,0.f,0.f}; bL[g]=z;
        }
#pragma unroll
        for (int kb=0;kb<8;kb++){
            const unsigned short* hb = (kb<4) ? h0hi[1-p] : h1hi[p];
            const unsigned short* lb = (kb<4) ? h0lo[1-p] : h1lo[p];
            int kk = kb & 3;
            v8s ah = *(const v8s*)&hb[kk*512 + ((l*8) ^ lsw)];
            v8s al = *(const v8s*)&lb[kk*512 + ((l*8) ^ lsw)];
#pragma unroll
            for (int g=0;g<4;g++){
                bH[g] = MFMA16(ah, as_v8s(W1r[g*8+kb]), bH[g]);
                bL[g] = MFMA16(al, as_v8s(W1r[g*8+kb]), bL[g]);
            }
        }
        float h1new[4];
#pragma unroll
        for (int i=0;i<4;i++){
            float gi_ = bH[0][i]+bL[0][i], gf_ = bH[1][i]+bL[1][i];
            float gg_ = bH[2][i]+bL[2][i], go_ = bH[3][i]+bL[3][i];
            c1[i] = fsig(gf_)*c1[i] + fsig(gi_)*ftanh(gg_);
            h1new[i] = fsig(go_)*ftanh(c1[i]);
            int row = q*4 + i;
            int off = (kbw*512 + (qw*16 + row)*8 + jw) ^ (((row>>1)&7)<<3);
            unsigned short h = f2bf(h1new[i]);
            h1hi[1-p][off] = h;
            h1lo[1-p][off] = f2bf(h1new[i] - bf2f(h));
        }

        // ---- out-proj deferred: stream h1 (f32) to global scratch ----
#pragma unroll
        for (int i=0;i<4;i++){
            h1buf[((size_t)(b0 + q*4 + i)*OUTL + t)*DEC + j] = h1new[i];
        }
        p ^= 1;
    }
}

// ---------------- out-projection: fut = h1buf @ Wop^T + bop (unchanged) ----------------
__global__ __launch_bounds__(256) void out_proj(
    const float* __restrict__ h1buf,
    const float* __restrict__ Wop, const float* __restrict__ bop,
    float* __restrict__ outp)
{
    int idx = blockIdx.x*256 + threadIdx.x;      // idx = b*OUTL + t
    if (idx >= BB*OUTL) return;
    const float4* hp = (const float4*)(h1buf + (size_t)idx*DEC);
    const float4* w0 = (const float4*)Wop;
    const float4* w1 = (const float4*)(Wop + DEC);
    float a0 = 0.f, a1 = 0.f;
#pragma unroll
    for (int k=0;k<32;k++){
        float4 h = hp[k], x0 = w0[k], x1 = w1[k];
        a0 += h.x*x0.x + h.y*x0.y + h.z*x0.z + h.w*x0.w;
        a1 += h.x*x1.x + h.y*x1.y + h.z*x1.z + h.w*x1.w;
    }
    outp[(size_t)idx*2    ] = a0 + bop[0];
    outp[(size_t)idx*2 + 1] = a1 + bop[1];
}

extern "C" void kernel_launch(void* const* d_in, const int* in_sizes, int n_in,
                              void* d_out, int out_size, void* d_ws, size_t ws_size,
                              hipStream_t stream)
{
    const float* x    = (const float*)d_in[0];
    const int*   ei   = (const int*)d_in[1];
    const float* ea   = (const float*)d_in[2];
    const int*   tgt  = (const int*)d_in[3];
    const float* Wip  = (const float*)d_in[4];
    const float* bip  = (const float*)d_in[5];
    const float* gWih = (const float*)d_in[6];
    const float* gWhh = (const float*)d_in[7];
    const float* gbih = (const float*)d_in[8];
    const float* gbhh = (const float*)d_in[9];
    const float* Wdyn = (const float*)d_in[10];
    const float* bdyn = (const float*)d_in[11];
    const float* c1Wf=(const float*)d_in[12]; const float* c1bf=(const float*)d_in[13];
    const float* c1Ws=(const float*)d_in[14]; const float* c1bs=(const float*)d_in[15];
    const float* c1g =(const float*)d_in[16]; const float* c1b =(const float*)d_in[17];
    const float* c1m =(const float*)d_in[18]; const float* c1v =(const float*)d_in[19];
    const float* c2Wf=(const float*)d_in[20]; const float* c2bf=(const float*)d_in[21];
    const float* c2Ws=(const float*)d_in[22]; const float* c2bs=(const float*)d_in[23];
    const float* c2g =(const float*)d_in[24]; const float* c2b =(const float*)d_in[25];
    const float* c2m =(const float*)d_in[26]; const float* c2v =(const float*)d_in[27];
    const float* Wn  =(const float*)d_in[28]; const float* bn_ =(const float*)d_in[29];
    const float* l0Wih=(const float*)d_in[30]; const float* l0Whh=(const float*)d_in[31];
    const float* l0bih=(const float*)d_in[32]; const float* l0bhh=(const float*)d_in[33];
    const float* l1Wih=(const float*)d_in[34]; const float* l1Whh=(const float*)d_in[35];
    const float* l1bih=(const float*)d_in[36]; const float* l1bhh=(const float*)d_in[37];
    const float* Wop =(const float*)d_in[38]; const float* bop=(const float*)d_in[39];

    float* ws = (float*)d_ws;
    size_t o = 0;
    float* hist = ws + o; o += (size_t)NN*ENC;
    float* f1   = ws + o; o += (size_t)NN*ENC;
    float* f2   = ws + o; o += (size_t)NN*ENC;
    float* Af   = ws + o; o += (size_t)NN*ENC;
    float* Bf   = ws + o; o += (size_t)NN*ENC;
    float* As   = ws + o; o += (size_t)NN*ENC;
    float* Bs   = ws + o; o += (size_t)NN*ENC;
    float* enc  = ws + o; o += (size_t)BB*2*ENC;
    float* gi0  = ws + o; o += (size_t)BB*4*DEC;
    unsigned short* pWih  = (unsigned short*)(ws + o); o += (size_t)12*64*8/2;
    unsigned short* pWhh  = (unsigned short*)(ws + o); o += (size_t)24*64*8/2;
    unsigned short* pWdyn = (unsigned short*)(ws + o); o += (size_t)8*64*8/2;
    unsigned short* B0h = (unsigned short*)(ws + o); o += (size_t)32*4*64*8/2;
    unsigned short* B1h = (unsigned short*)(ws + o); o += (size_t)32*8*64*8/2;
    unsigned short* P1h = (unsigned short*)(ws + o); o += (size_t)2048*8/2;
    unsigned short* P1l = (unsigned short*)(ws + o); o += (size_t)2048*8/2;
    unsigned short* P2h = (unsigned short*)(ws + o); o += (size_t)2048*8/2;
    unsigned short* P2l = (unsigned short*)(ws + o); o += (size_t)2048*8/2;
    unsigned short* GIh = (unsigned short*)(ws + o); o += (size_t)8192*8/2;
    unsigned short* GIl = (unsigned short*)(ws + o); o += (size_t)8192*8/2;
    int* cnt    = (int*)(ws + o); o += NN;
    int* offv   = (int*)(ws + o); o += NN+1;
    int* curv   = (int*)(ws + o); o += NN;
    int* gtot   = (int*)(ws + o); o += 1;
    o = (o + 3) & ~(size_t)3;               // align to 16B for int4 records
    int4* recS  = (int4*)(ws + o); o += (size_t)4*EE;

    // h1buf (BB*OUTL*DEC = 6.4M floats) aliases Af..Bf (2*NN*ENC = 6.4M floats):
    // Af/Bf are dead after cg_agg #2, which completes (stream-ordered) before
    // lstm_mfma runs.
    float* h1buf = Af;

    // --- all weight prep + cnt/gtot zero in one dispatch ---
    pack_all<<<(PACK_TOTAL+255)/256, 256, 0, stream>>>(
        gWih, gWhh, Wdyn, l0Whh, l1Wih, l1Whh, l0Wih,
        c1Wf, c1Ws, c2Wf, c2Ws,
        pWih, pWhh, pWdyn, B0h, B1h, P1h, P1l, P2h, P2l, GIh, GIl, cnt, gtot);

    // --- dst segment build (order-free atomic allocation) ---
    count_kernel<<<(EE+255)/256, 256, 0, stream>>>(ei, cnt);
    alloc_kernel<<<(NN+255)/256, 256, 0, stream>>>(cnt, gtot, offv, curv);
    scatter_kernel<<<(EE+255)/256, 256, 0, stream>>>(ei, ea, curv, recS);

    // --- history encoder (MFMA, 40KB LDS -> 4 blocks/CU) ---
    encoder_mfma<<<NN/16, 256, 0, stream>>>(x, Wip, bip, pWih, pWhh, gbih, gbhh, pWdyn, bdyn, hist);

    // --- CGConv 1 ---
    proj_mfma<<<(NN+63)/64, 256, 0, stream>>>(hist, P1h, P1l, Af,Bf,As,Bs);
    cg_agg<<<(NN+3)/4, 256, 0, stream>>>(hist, recS, offv, cnt,
                                         c1Wf,c1bf,c1Ws,c1bs, Af,Bf,As,Bs,
                                         c1g,c1b,c1m,c1v, f1);

    // --- CGConv 2 ---
    proj_mfma<<<(NN+63)/64, 256, 0, stream>>>(f1, P2h, P2l, Af,Bf,As,Bs);
    cg_agg<<<(NN+3)/4, 256, 0, stream>>>(f1, recS, offv, cnt,
                                         c2Wf,c2bf,c2Ws,c2bs, Af,Bf,As,Bs,
                                         c2g,c2b,c2m,c2v, f2);

    // --- target encoding ---
    target_kernel<<<(BB+3)/4, 256, 0, stream>>>(hist, f2, tgt, Wn, bn_, enc);

    // --- LSTM decoder prep (MFMA gi0) ---
    gi0_mfma<<<BB/16, 512, 0, stream>>>(enc, GIh, GIl, l0bih, l0bhh, gi0);

    // --- LSTM decoder (out-proj deferred to scratch) ---
    lstm_mfma<<<BB/LMB, 512, 0, stream>>>(gi0, B0h, B1h,
                                          l1bih, l1bhh, h1buf);

    // --- out-projection ---
    out_proj<<<(BB*OUTL+255)/256, 256, 0, stream>>>(h1buf, Wop, bop, (float*)d_out);
}